// Round 1
// baseline (3624.344 us; speedup 1.0000x reference)
//
#include <hip/hip_runtime.h>
#include <hip/hip_bf16.h>

#define N_NODES 50000
#define N_EDGES 800000
#define E_TOT   850000   // edges + self loops
#define IN_DIM  128
#define C1      256      // HEADS*HID
#define HEADS   4
#define HID     64
#define OUT_DIM 32
#define NEG_SLOPE 0.2f

// ---------------------------------------------------------------- GEMM1
// h1[50000,256] = x[50000,128] @ W1[128,256]
// block: 256 thr = 4 waves; each wave handles 4 rows, each thread 4 rows x 4 cols
__global__ __launch_bounds__(256) void gemm1_kernel(const float* __restrict__ x,
                                                    const float* __restrict__ W,
                                                    float* __restrict__ h1) {
    __shared__ float xs[16][IN_DIM];
    const int t = threadIdx.x;
    const int row0 = blockIdx.x * 16;
    for (int i = t; i < 16 * IN_DIM; i += 256) {
        int r = i >> 7, k = i & 127;
        xs[r][k] = x[(size_t)(row0 + r) * IN_DIM + k];
    }
    __syncthreads();
    const int cg = (t & 63) * 4;   // col base (wave covers full 256-col row)
    const int rg = (t >> 6) * 4;   // row base (wave-uniform)
    float acc[4][4] = {};
#pragma unroll 4
    for (int k = 0; k < IN_DIM; ++k) {
        const float4 w = *(const float4*)&W[k * C1 + cg];
#pragma unroll
        for (int r = 0; r < 4; ++r) {
            float xv = xs[rg + r][k];
            acc[r][0] += xv * w.x;
            acc[r][1] += xv * w.y;
            acc[r][2] += xv * w.z;
            acc[r][3] += xv * w.w;
        }
    }
#pragma unroll
    for (int r = 0; r < 4; ++r) {
        float4 o = make_float4(acc[r][0], acc[r][1], acc[r][2], acc[r][3]);
        *(float4*)&h1[(size_t)(row0 + rg + r) * C1 + cg] = o;
    }
}

// ---------------------------------------------------------------- alpha1
// as1[n,h] = dot(h1[n,h*64:(h+1)*64], a_src1[h]);  ad1 likewise
__global__ __launch_bounds__(256) void alpha1_kernel(const float* __restrict__ h1,
                                                     const float* __restrict__ a_src,
                                                     const float* __restrict__ a_dst,
                                                     float* __restrict__ as1,
                                                     float* __restrict__ ad1) {
    int i = blockIdx.x * 256 + threadIdx.x;
    if (i >= N_NODES * HEADS) return;
    int n = i >> 2, h = i & 3;
    const float* hp = h1 + (size_t)n * C1 + h * HID;
    const float* ap = a_src + h * HID;
    const float* bp = a_dst + h * HID;
    float s = 0.f, d = 0.f;
#pragma unroll
    for (int f = 0; f < HID; f += 4) {
        float4 hv = *(const float4*)&hp[f];
        float4 av = *(const float4*)&ap[f];
        float4 bv = *(const float4*)&bp[f];
        s += hv.x * av.x + hv.y * av.y + hv.z * av.z + hv.w * av.w;
        d += hv.x * bv.x + hv.y * bv.y + hv.z * bv.z + hv.w * bv.w;
    }
    as1[i] = s;
    ad1[i] = d;
}

// ---------------------------------------------------------------- edge pass 1 (layer 1)
// w1e[e,h] = exp(leaky_relu(as1[src,h]+ad1[dst,h])); sum1[dst,h] += w1e
__global__ __launch_bounds__(256) void edge1a_kernel(const int* __restrict__ ei,
                                                     const float* __restrict__ as1,
                                                     const float* __restrict__ ad1,
                                                     float* __restrict__ w1e,
                                                     float* __restrict__ sum1) {
    int e = blockIdx.x * 256 + threadIdx.x;
    if (e >= E_TOT) return;
    int s, d;
    if (e < N_EDGES) { s = ei[e]; d = ei[N_EDGES + e]; }
    else             { s = d = e - N_EDGES; }
    float4 av = *(const float4*)&as1[s * 4];
    float4 bv = *(const float4*)&ad1[d * 4];
    float l0 = av.x + bv.x, l1 = av.y + bv.y, l2 = av.z + bv.z, l3 = av.w + bv.w;
    l0 = l0 > 0.f ? l0 : NEG_SLOPE * l0;
    l1 = l1 > 0.f ? l1 : NEG_SLOPE * l1;
    l2 = l2 > 0.f ? l2 : NEG_SLOPE * l2;
    l3 = l3 > 0.f ? l3 : NEG_SLOPE * l3;
    float w0 = expf(l0), w1 = expf(l1), w2 = expf(l2), w3 = expf(l3);
    *(float4*)&w1e[e * 4] = make_float4(w0, w1, w2, w3);
    atomicAdd(&sum1[d * 4 + 0], w0);
    atomicAdd(&sum1[d * 4 + 1], w1);
    atomicAdd(&sum1[d * 4 + 2], w2);
    atomicAdd(&sum1[d * 4 + 3], w3);
}

// ---------------------------------------------------------------- edge pass 2 (layer 1)
// agg[dst,:] += h1[src,:] * (w1e[e,h]/(sum1[dst,h]+1e-16))
// block = 4 edges x 64 lanes, float4 per lane
__global__ __launch_bounds__(256) void edge1b_kernel(const int* __restrict__ ei,
                                                     const float* __restrict__ h1,
                                                     const float* __restrict__ w1e,
                                                     const float* __restrict__ sum1,
                                                     float* __restrict__ agg) {
    int e = blockIdx.x * 4 + (threadIdx.x >> 6);
    int lane = threadIdx.x & 63;
    int s, d;
    if (e < N_EDGES) { s = ei[e]; d = ei[N_EDGES + e]; }
    else             { s = d = e - N_EDGES; }
    int h = lane >> 4;  // 16 lanes (64 floats) per head
    float coeff = w1e[e * 4 + h] / (sum1[d * 4 + h] + 1e-16f);
    float4 hv = *(const float4*)&h1[(size_t)s * C1 + lane * 4];
    float* op = &agg[(size_t)d * C1 + lane * 4];
    atomicAdd(op + 0, hv.x * coeff);
    atomicAdd(op + 1, hv.y * coeff);
    atomicAdd(op + 2, hv.z * coeff);
    atomicAdd(op + 3, hv.w * coeff);
}

// ---------------------------------------------------------------- post1: bias + ELU
__global__ __launch_bounds__(256) void post1_kernel(float* __restrict__ agg,
                                                    const float* __restrict__ b1) {
    int i = blockIdx.x * 256 + threadIdx.x;
    if (i >= N_NODES * C1) return;
    float v = agg[i] + b1[i & 255];
    agg[i] = v > 0.f ? v : expf(v) - 1.f;
}

// ---------------------------------------------------------------- GEMM2
// h2[50000,32] = hp[50000,256] @ W2[256,32]; block = 8 rows x 32 cols
__global__ __launch_bounds__(256) void gemm2_kernel(const float* __restrict__ hp,
                                                    const float* __restrict__ W,
                                                    float* __restrict__ h2) {
    __shared__ float w2s[C1 * OUT_DIM];  // 32 KB
    __shared__ float xr[8][C1];          // 8 KB
    const int t = threadIdx.x;
    const int row0 = blockIdx.x * 8;
    for (int i = t; i < C1 * OUT_DIM; i += 256) w2s[i] = W[i];
    for (int i = t; i < 8 * C1; i += 256) {
        int r = i >> 8, k = i & 255;
        xr[r][k] = hp[(size_t)(row0 + r) * C1 + k];
    }
    __syncthreads();
    const int r = t >> 5, c = t & 31;
    float acc = 0.f;
#pragma unroll 8
    for (int k = 0; k < C1; ++k) acc += xr[r][k] * w2s[k * OUT_DIM + c];
    h2[(size_t)(row0 + r) * OUT_DIM + c] = acc;
}

// ---------------------------------------------------------------- alpha2
__global__ __launch_bounds__(256) void alpha2_kernel(const float* __restrict__ h2,
                                                     const float* __restrict__ a_src,
                                                     const float* __restrict__ a_dst,
                                                     float* __restrict__ as2,
                                                     float* __restrict__ ad2) {
    int n = blockIdx.x * 256 + threadIdx.x;
    if (n >= N_NODES) return;
    const float* hp = h2 + (size_t)n * OUT_DIM;
    float s = 0.f, d = 0.f;
#pragma unroll
    for (int f = 0; f < OUT_DIM; f += 4) {
        float4 hv = *(const float4*)&hp[f];
        float4 av = *(const float4*)&a_src[f];
        float4 bv = *(const float4*)&a_dst[f];
        s += hv.x * av.x + hv.y * av.y + hv.z * av.z + hv.w * av.w;
        d += hv.x * bv.x + hv.y * bv.y + hv.z * bv.z + hv.w * bv.w;
    }
    as2[n] = s;
    ad2[n] = d;
}

// ---------------------------------------------------------------- edge pass 1 (layer 2)
__global__ __launch_bounds__(256) void edge2a_kernel(const int* __restrict__ ei,
                                                     const float* __restrict__ as2,
                                                     const float* __restrict__ ad2,
                                                     float* __restrict__ w2e,
                                                     float* __restrict__ sum2) {
    int e = blockIdx.x * 256 + threadIdx.x;
    if (e >= E_TOT) return;
    int s, d;
    if (e < N_EDGES) { s = ei[e]; d = ei[N_EDGES + e]; }
    else             { s = d = e - N_EDGES; }
    float l = as2[s] + ad2[d];
    l = l > 0.f ? l : NEG_SLOPE * l;
    float w = expf(l);
    w2e[e] = w;
    atomicAdd(&sum2[d], w);
}

// ---------------------------------------------------------------- edge pass 2 (layer 2)
// out[dst,:] += h2[src,:]*coeff ; block = 32 edges x 8 lanes x float4
__global__ __launch_bounds__(256) void edge2b_kernel(const int* __restrict__ ei,
                                                     const float* __restrict__ h2,
                                                     const float* __restrict__ w2e,
                                                     const float* __restrict__ sum2,
                                                     float* __restrict__ out) {
    int e = blockIdx.x * 32 + (threadIdx.x >> 3);
    if (e >= E_TOT) return;
    int lane = threadIdx.x & 7;
    int s, d;
    if (e < N_EDGES) { s = ei[e]; d = ei[N_EDGES + e]; }
    else             { s = d = e - N_EDGES; }
    float coeff = w2e[e] / (sum2[d] + 1e-16f);
    float4 hv = *(const float4*)&h2[(size_t)s * OUT_DIM + lane * 4];
    float* op = &out[(size_t)d * OUT_DIM + lane * 4];
    atomicAdd(op + 0, hv.x * coeff);
    atomicAdd(op + 1, hv.y * coeff);
    atomicAdd(op + 2, hv.z * coeff);
    atomicAdd(op + 3, hv.w * coeff);
}

// ---------------------------------------------------------------- post2: +b2
__global__ __launch_bounds__(256) void post2_kernel(float* __restrict__ out,
                                                    const float* __restrict__ b2) {
    int i = blockIdx.x * 256 + threadIdx.x;
    if (i >= N_NODES * OUT_DIM) return;
    out[i] += b2[i & 31];
}

extern "C" void kernel_launch(void* const* d_in, const int* in_sizes, int n_in,
                              void* d_out, int out_size, void* d_ws, size_t ws_size,
                              hipStream_t stream) {
    const float* x      = (const float*)d_in[0];
    const int*   ei     = (const int*)d_in[1];
    const float* W1     = (const float*)d_in[2];
    const float* a_src1 = (const float*)d_in[3];
    const float* a_dst1 = (const float*)d_in[4];
    const float* b1     = (const float*)d_in[5];
    const float* W2     = (const float*)d_in[6];
    const float* a_src2 = (const float*)d_in[7];
    const float* a_dst2 = (const float*)d_in[8];
    const float* b2     = (const float*)d_in[9];
    float* out = (float*)d_out;

    // workspace layout (floats)
    float* wsf  = (float*)d_ws;
    float* h1   = wsf;                    // 12,800,000
    float* agg  = h1 + 12800000;          // 12,800,000
    float* as1  = agg + 12800000;         // 200,000
    float* ad1  = as1 + 200000;           // 200,000
    float* sum1 = ad1 + 200000;           // 200,000
    float* w1e  = sum1 + 200000;          // 3,400,000  -> total 29.6M floats = 118.4 MB
    // layer-2 temporaries overlay the dead h1 region:
    float* h2   = wsf;                    // 1,600,000
    float* as2  = wsf + 1600000;          // 50,000
    float* ad2  = as2 + 50000;            // 50,000
    float* sum2 = ad2 + 50000;            // 50,000
    float* w2e  = sum2 + 50000;           // 850,000

    // zero accumulators (ws/d_out are poisoned 0xAA before every launch)
    hipMemsetAsync(agg, 0, (size_t)12800000 * 4, stream);
    hipMemsetAsync(sum1, 0, (size_t)200000 * 4, stream);
    hipMemsetAsync(d_out, 0, (size_t)N_NODES * OUT_DIM * 4, stream);

    gemm1_kernel<<<N_NODES / 16, 256, 0, stream>>>(x, W1, h1);
    alpha1_kernel<<<(N_NODES * HEADS + 255) / 256, 256, 0, stream>>>(h1, a_src1, a_dst1, as1, ad1);
    edge1a_kernel<<<(E_TOT + 255) / 256, 256, 0, stream>>>(ei, as1, ad1, w1e, sum1);
    edge1b_kernel<<<E_TOT / 4, 256, 0, stream>>>(ei, h1, w1e, sum1, agg);
    post1_kernel<<<(N_NODES * C1 + 255) / 256, 256, 0, stream>>>(agg, b1);

    // h1 is dead now; overlay region becomes valid
    hipMemsetAsync(sum2, 0, (size_t)N_NODES * 4, stream);
    gemm2_kernel<<<N_NODES / 8, 256, 0, stream>>>(agg, W2, h2);
    alpha2_kernel<<<(N_NODES + 255) / 256, 256, 0, stream>>>(h2, a_src2, a_dst2, as2, ad2);
    edge2a_kernel<<<(E_TOT + 255) / 256, 256, 0, stream>>>(ei, as2, ad2, w2e, sum2);
    edge2b_kernel<<<(E_TOT + 31) / 32, 256, 0, stream>>>(ei, h2, w2e, sum2, out);
    post2_kernel<<<(N_NODES * OUT_DIM + 255) / 256, 256, 0, stream>>>(out, b2);
}

// Round 2
// 467.664 us; speedup vs baseline: 7.7499x; 7.7499x over previous
//
#include <hip/hip_runtime.h>
#include <hip/hip_bf16.h>

#define N_NODES 50000
#define N_EDGES 800000
#define E_TOT   850000   // edges + self loops
#define IN_DIM  128
#define C1      256      // HEADS*HID
#define HEADS   4
#define HID     64
#define OUT_DIM 32
#define NEG_SLOPE 0.2f
#define SCAN_NBLK 196    // ceil(50000/256)

__device__ __forceinline__ void edge_sd(const int* __restrict__ ei, int e, int& s, int& d) {
    if (e < N_EDGES) { s = ei[e]; d = ei[N_EDGES + e]; }
    else             { s = d = e - N_EDGES; }
}

// ================================================================ CSR build
__global__ __launch_bounds__(256) void deg_kernel(const int* __restrict__ ei,
                                                  int* __restrict__ deg) {
    int e = blockIdx.x * 256 + threadIdx.x;
    if (e >= E_TOT) return;
    int s, d; edge_sd(ei, e, s, d);
    atomicAdd(&deg[d], 1);
}

// per-256-chunk inclusive scan
__global__ __launch_bounds__(256) void scanA_kernel(const int* __restrict__ deg,
                                                    int* __restrict__ incl,
                                                    int* __restrict__ blocksum) {
    __shared__ int sm[256];
    int t = threadIdx.x, idx = blockIdx.x * 256 + t;
    int v = (idx < N_NODES) ? deg[idx] : 0;
    sm[t] = v; __syncthreads();
#pragma unroll
    for (int off = 1; off < 256; off <<= 1) {
        int u = (t >= off) ? sm[t - off] : 0;
        __syncthreads();
        sm[t] += u;
        __syncthreads();
    }
    if (idx < N_NODES) incl[idx] = sm[t];
    if (t == 255) blocksum[blockIdx.x] = sm[t];
}

// exclusive scan of block sums (single block)
__global__ __launch_bounds__(256) void scanB_kernel(const int* __restrict__ blocksum,
                                                    int* __restrict__ blockoff) {
    __shared__ int sm[256];
    int t = threadIdx.x;
    int v = (t < SCAN_NBLK) ? blocksum[t] : 0;
    sm[t] = v; __syncthreads();
#pragma unroll
    for (int off = 1; off < 256; off <<= 1) {
        int u = (t >= off) ? sm[t - off] : 0;
        __syncthreads();
        sm[t] += u;
        __syncthreads();
    }
    if (t < SCAN_NBLK) blockoff[t] = sm[t] - v;  // exclusive
}

__global__ __launch_bounds__(256) void scanC_kernel(const int* __restrict__ deg,
                                                    const int* __restrict__ incl,
                                                    const int* __restrict__ blockoff,
                                                    int* __restrict__ row_start) {
    int idx = blockIdx.x * 256 + threadIdx.x;
    if (idx >= N_NODES) return;
    int off = blockoff[idx >> 8];
    row_start[idx] = off + incl[idx] - deg[idx];
    if (idx == N_NODES - 1) row_start[N_NODES] = off + incl[idx];  // == E_TOT
}

__global__ __launch_bounds__(256) void scatter_kernel(const int* __restrict__ ei,
                                                      const int* __restrict__ row_start,
                                                      int* __restrict__ cursor,
                                                      int* __restrict__ csr_src) {
    int e = blockIdx.x * 256 + threadIdx.x;
    if (e >= E_TOT) return;
    int s, d; edge_sd(ei, e, s, d);
    int pos = atomicAdd(&cursor[d], 1);
    csr_src[row_start[d] + pos] = s;
}

// ================================================================ GEMM1
// h1[50000,256] = x[50000,128] @ W1[128,256]
__global__ __launch_bounds__(256) void gemm1_kernel(const float* __restrict__ x,
                                                    const float* __restrict__ W,
                                                    float* __restrict__ h1) {
    __shared__ float xs[16][IN_DIM];
    const int t = threadIdx.x;
    const int row0 = blockIdx.x * 16;
    for (int i = t; i < 16 * IN_DIM; i += 256) {
        int r = i >> 7, k = i & 127;
        xs[r][k] = x[(size_t)(row0 + r) * IN_DIM + k];
    }
    __syncthreads();
    const int cg = (t & 63) * 4;
    const int rg = (t >> 6) * 4;
    float acc[4][4] = {};
#pragma unroll 4
    for (int k = 0; k < IN_DIM; ++k) {
        const float4 w = *(const float4*)&W[k * C1 + cg];
#pragma unroll
        for (int r = 0; r < 4; ++r) {
            float xv = xs[rg + r][k];
            acc[r][0] += xv * w.x;
            acc[r][1] += xv * w.y;
            acc[r][2] += xv * w.z;
            acc[r][3] += xv * w.w;
        }
    }
#pragma unroll
    for (int r = 0; r < 4; ++r) {
        float4 o = make_float4(acc[r][0], acc[r][1], acc[r][2], acc[r][3]);
        *(float4*)&h1[(size_t)(row0 + rg + r) * C1 + cg] = o;
    }
}

// ================================================================ alpha1
__global__ __launch_bounds__(256) void alpha1_kernel(const float* __restrict__ h1,
                                                     const float* __restrict__ a_src,
                                                     const float* __restrict__ a_dst,
                                                     float* __restrict__ as1,
                                                     float* __restrict__ ad1) {
    int i = blockIdx.x * 256 + threadIdx.x;
    if (i >= N_NODES * HEADS) return;
    int n = i >> 2, h = i & 3;
    const float* hp = h1 + (size_t)n * C1 + h * HID;
    const float* ap = a_src + h * HID;
    const float* bp = a_dst + h * HID;
    float s = 0.f, d = 0.f;
#pragma unroll
    for (int f = 0; f < HID; f += 4) {
        float4 hv = *(const float4*)&hp[f];
        float4 av = *(const float4*)&ap[f];
        float4 bv = *(const float4*)&bp[f];
        s += hv.x * av.x + hv.y * av.y + hv.z * av.z + hv.w * av.w;
        d += hv.x * bv.x + hv.y * bv.y + hv.z * bv.z + hv.w * bv.w;
    }
    as1[i] = s;
    ad1[i] = d;
}

// ================================================================ agg1: fused softmax+aggregate+bias+ELU, 1 wave/dst
// hp[n,:] = ELU( (sum_e w_e * h1[src_e,:]) / (sum_e w_e) + b1 ),  w_e = exp(lrelu(as1+ad1))
__global__ __launch_bounds__(256) void agg1_kernel(const int* __restrict__ csr_src,
                                                   const int* __restrict__ row_start,
                                                   const float* __restrict__ h1,
                                                   const float* __restrict__ as1,
                                                   const float* __restrict__ ad1,
                                                   const float* __restrict__ b1,
                                                   float* __restrict__ hp) {
    int n = (blockIdx.x * 256 + threadIdx.x) >> 6;  // dst node (1 wave each)
    if (n >= N_NODES) return;
    int lane = threadIdx.x & 63;
    int h = lane >> 4;
    int beg = row_start[n], end = row_start[n + 1];
    float ad = ad1[n * 4 + h];
    float4 acc = make_float4(0.f, 0.f, 0.f, 0.f);
    float sumw = 0.f;
    for (int i = beg; i < end; ++i) {
        int s = csr_src[i];
        float l = as1[s * 4 + h] + ad;
        l = l > 0.f ? l : NEG_SLOPE * l;
        float w = __expf(l);
        sumw += w;
        float4 hv = *(const float4*)&h1[(size_t)s * C1 + lane * 4];
        acc.x += w * hv.x;
        acc.y += w * hv.y;
        acc.z += w * hv.z;
        acc.w += w * hv.w;
    }
    float inv = 1.f / (sumw + 1e-16f);
    const float4 bv = *(const float4*)&b1[lane * 4];
    float v0 = acc.x * inv + bv.x;
    float v1 = acc.y * inv + bv.y;
    float v2 = acc.z * inv + bv.z;
    float v3 = acc.w * inv + bv.w;
    v0 = v0 > 0.f ? v0 : __expf(v0) - 1.f;
    v1 = v1 > 0.f ? v1 : __expf(v1) - 1.f;
    v2 = v2 > 0.f ? v2 : __expf(v2) - 1.f;
    v3 = v3 > 0.f ? v3 : __expf(v3) - 1.f;
    *(float4*)&hp[(size_t)n * C1 + lane * 4] = make_float4(v0, v1, v2, v3);
}

// ================================================================ GEMM2
__global__ __launch_bounds__(256) void gemm2_kernel(const float* __restrict__ hp,
                                                    const float* __restrict__ W,
                                                    float* __restrict__ h2) {
    __shared__ float w2s[C1 * OUT_DIM];  // 32 KB
    __shared__ float xr[8][C1];          // 8 KB
    const int t = threadIdx.x;
    const int row0 = blockIdx.x * 8;
    for (int i = t; i < C1 * OUT_DIM; i += 256) w2s[i] = W[i];
    for (int i = t; i < 8 * C1; i += 256) {
        int r = i >> 8, k = i & 255;
        xr[r][k] = hp[(size_t)(row0 + r) * C1 + k];
    }
    __syncthreads();
    const int r = t >> 5, c = t & 31;
    float acc = 0.f;
#pragma unroll 8
    for (int k = 0; k < C1; ++k) acc += xr[r][k] * w2s[k * OUT_DIM + c];
    h2[(size_t)(row0 + r) * OUT_DIM + c] = acc;
}

// ================================================================ alpha2
__global__ __launch_bounds__(256) void alpha2_kernel(const float* __restrict__ h2,
                                                     const float* __restrict__ a_src,
                                                     const float* __restrict__ a_dst,
                                                     float* __restrict__ as2,
                                                     float* __restrict__ ad2) {
    int n = blockIdx.x * 256 + threadIdx.x;
    if (n >= N_NODES) return;
    const float* hp = h2 + (size_t)n * OUT_DIM;
    float s = 0.f, d = 0.f;
#pragma unroll
    for (int f = 0; f < OUT_DIM; f += 4) {
        float4 hv = *(const float4*)&hp[f];
        float4 av = *(const float4*)&a_src[f];
        float4 bv = *(const float4*)&a_dst[f];
        s += hv.x * av.x + hv.y * av.y + hv.z * av.z + hv.w * av.w;
        d += hv.x * bv.x + hv.y * bv.y + hv.z * bv.z + hv.w * bv.w;
    }
    as2[n] = s;
    ad2[n] = d;
}

// ================================================================ agg2: fused softmax+aggregate+bias, 8 dst/wave
__global__ __launch_bounds__(256) void agg2_kernel(const int* __restrict__ csr_src,
                                                   const int* __restrict__ row_start,
                                                   const float* __restrict__ h2,
                                                   const float* __restrict__ as2,
                                                   const float* __restrict__ ad2,
                                                   const float* __restrict__ b2,
                                                   float* __restrict__ out) {
    int wave = (blockIdx.x * 256 + threadIdx.x) >> 6;
    int lane = threadIdx.x & 63;
    int seg = lane >> 3;          // 8 segments of 8 lanes
    int sub = lane & 7;           // covers 32 floats as 8 x float4
    int n = wave * 8 + seg;
    if (n >= N_NODES) return;
    int beg = row_start[n], end = row_start[n + 1];
    float ad = ad2[n];
    float4 acc = make_float4(0.f, 0.f, 0.f, 0.f);
    float sumw = 0.f;
    for (int i = beg; i < end; ++i) {
        int s = csr_src[i];
        float l = as2[s] + ad;
        l = l > 0.f ? l : NEG_SLOPE * l;
        float w = __expf(l);
        sumw += w;
        float4 hv = *(const float4*)&h2[(size_t)s * OUT_DIM + sub * 4];
        acc.x += w * hv.x;
        acc.y += w * hv.y;
        acc.z += w * hv.z;
        acc.w += w * hv.w;
    }
    float inv = 1.f / (sumw + 1e-16f);
    const float4 bv = *(const float4*)&b2[sub * 4];
    *(float4*)&out[(size_t)n * OUT_DIM + sub * 4] =
        make_float4(acc.x * inv + bv.x, acc.y * inv + bv.y,
                    acc.z * inv + bv.z, acc.w * inv + bv.w);
}

extern "C" void kernel_launch(void* const* d_in, const int* in_sizes, int n_in,
                              void* d_out, int out_size, void* d_ws, size_t ws_size,
                              hipStream_t stream) {
    const float* x      = (const float*)d_in[0];
    const int*   ei     = (const int*)d_in[1];
    const float* W1     = (const float*)d_in[2];
    const float* a_src1 = (const float*)d_in[3];
    const float* a_dst1 = (const float*)d_in[4];
    const float* b1     = (const float*)d_in[5];
    const float* W2     = (const float*)d_in[6];
    const float* a_src2 = (const float*)d_in[7];
    const float* a_dst2 = (const float*)d_in[8];
    const float* b2     = (const float*)d_in[9];
    float* out = (float*)d_out;

    // workspace layout (4-byte elements)
    float* wsf    = (float*)d_ws;
    float* h1     = wsf;                    // 12.8M
    float* hp     = h1 + 12800000;          // 12.8M
    float* h2     = hp + 12800000;          // 1.6M
    float* as1    = h2 + 1600000;           // 200k
    float* ad1    = as1 + 200000;           // 200k
    float* as2    = ad1 + 200000;           // 50k
    float* ad2    = as2 + 50000;            // 50k
    int* csr_src  = (int*)(ad2 + 50000);    // 850k
    int* row_start= csr_src + E_TOT;        // 50001
    int* deg      = row_start + (N_NODES+1);// 50k
    int* cursor   = deg + N_NODES;          // 50k
    int* incl     = cursor + N_NODES;       // 50k
    int* blocksum = incl + N_NODES;         // 256
    int* blockoff = blocksum + 256;         // 256  -> total ~29.0M elems = 116 MB

    hipMemsetAsync(deg, 0, (size_t)N_NODES * 4, stream);
    hipMemsetAsync(cursor, 0, (size_t)N_NODES * 4, stream);

    const int EB = (E_TOT + 255) / 256;
    // CSR build (shared by both layers)
    deg_kernel<<<EB, 256, 0, stream>>>(ei, deg);
    scanA_kernel<<<SCAN_NBLK, 256, 0, stream>>>(deg, incl, blocksum);
    scanB_kernel<<<1, 256, 0, stream>>>(blocksum, blockoff);
    scanC_kernel<<<SCAN_NBLK, 256, 0, stream>>>(deg, incl, blockoff, row_start);
    scatter_kernel<<<EB, 256, 0, stream>>>(ei, row_start, cursor, csr_src);

    // layer 1
    gemm1_kernel<<<N_NODES / 16, 256, 0, stream>>>(x, W1, h1);
    alpha1_kernel<<<(N_NODES * HEADS + 255) / 256, 256, 0, stream>>>(h1, a_src1, a_dst1, as1, ad1);
    agg1_kernel<<<(N_NODES * 64 + 255) / 256, 256, 0, stream>>>(csr_src, row_start, h1, as1, ad1, b1, hp);

    // layer 2
    gemm2_kernel<<<N_NODES / 8, 256, 0, stream>>>(hp, W2, h2);
    alpha2_kernel<<<(N_NODES + 255) / 256, 256, 0, stream>>>(h2, a_src2, a_dst2, as2, ad2);
    agg2_kernel<<<(((N_NODES + 7) / 8) * 64 + 255) / 256, 256, 0, stream>>>(csr_src, row_start, h2, as2, ad2, b2, out);
}

// Round 3
// 415.947 us; speedup vs baseline: 8.7135x; 1.1243x over previous
//
#include <hip/hip_runtime.h>
#include <hip/hip_bf16.h>

#define N_NODES 50000
#define N_EDGES 800000
#define E_TOT   850000   // edges + self loops
#define IN_DIM  128
#define C1      256      // HEADS*HID
#define HEADS   4
#define HID     64
#define OUT_DIM 32
#define NEG_SLOPE 0.2f
#define SCAN_NBLK 196    // ceil(50000/256)

__device__ __forceinline__ void edge_sd(const int* __restrict__ ei, int e, int& s, int& d) {
    if (e < N_EDGES) { s = ei[e]; d = ei[N_EDGES + e]; }
    else             { s = d = e - N_EDGES; }
}

__device__ __forceinline__ unsigned short f2bf(float f) {
    unsigned u = __float_as_uint(f);
    u += 0x7fffu + ((u >> 16) & 1u);   // RNE
    return (unsigned short)(u >> 16);
}
__device__ __forceinline__ float bf2f(unsigned short u) {
    return __uint_as_float(((unsigned)u) << 16);
}
__device__ __forceinline__ float4 bf4_to_f4(ushort4 v) {
    return make_float4(bf2f(v.x), bf2f(v.y), bf2f(v.z), bf2f(v.w));
}

// ================================================================ CSR build
__global__ __launch_bounds__(256) void deg_kernel(const int* __restrict__ ei,
                                                  int* __restrict__ deg) {
    int e = blockIdx.x * 256 + threadIdx.x;
    if (e >= E_TOT) return;
    int s, d; edge_sd(ei, e, s, d);
    atomicAdd(&deg[d], 1);
}

__global__ __launch_bounds__(256) void scanA_kernel(const int* __restrict__ deg,
                                                    int* __restrict__ incl,
                                                    int* __restrict__ blocksum) {
    __shared__ int sm[256];
    int t = threadIdx.x, idx = blockIdx.x * 256 + t;
    int v = (idx < N_NODES) ? deg[idx] : 0;
    sm[t] = v; __syncthreads();
#pragma unroll
    for (int off = 1; off < 256; off <<= 1) {
        int u = (t >= off) ? sm[t - off] : 0;
        __syncthreads();
        sm[t] += u;
        __syncthreads();
    }
    if (idx < N_NODES) incl[idx] = sm[t];
    if (t == 255) blocksum[blockIdx.x] = sm[t];
}

__global__ __launch_bounds__(256) void scanB_kernel(const int* __restrict__ blocksum,
                                                    int* __restrict__ blockoff) {
    __shared__ int sm[256];
    int t = threadIdx.x;
    int v = (t < SCAN_NBLK) ? blocksum[t] : 0;
    sm[t] = v; __syncthreads();
#pragma unroll
    for (int off = 1; off < 256; off <<= 1) {
        int u = (t >= off) ? sm[t - off] : 0;
        __syncthreads();
        sm[t] += u;
        __syncthreads();
    }
    if (t < SCAN_NBLK) blockoff[t] = sm[t] - v;  // exclusive
}

__global__ __launch_bounds__(256) void scanC_kernel(const int* __restrict__ deg,
                                                    const int* __restrict__ incl,
                                                    const int* __restrict__ blockoff,
                                                    int* __restrict__ row_start) {
    int idx = blockIdx.x * 256 + threadIdx.x;
    if (idx >= N_NODES) return;
    int off = blockoff[idx >> 8];
    row_start[idx] = off + incl[idx] - deg[idx];
    if (idx == N_NODES - 1) row_start[N_NODES] = off + incl[idx];  // == E_TOT
}

__global__ __launch_bounds__(256) void scatter_kernel(const int* __restrict__ ei,
                                                      const int* __restrict__ row_start,
                                                      int* __restrict__ cursor,
                                                      int* __restrict__ csr_src) {
    int e = blockIdx.x * 256 + threadIdx.x;
    if (e >= E_TOT) return;
    int s, d; edge_sd(ei, e, s, d);
    int pos = atomicAdd(&cursor[d], 1);
    csr_src[row_start[d] + pos] = s;
}

// ================================================================ GEMM1
// h1b[50000,256](bf16) = x[50000,128] @ W1[128,256]; fp32 accumulate, RNE at store
// 32-row tile, 8 rows/thread -> 2x W-reuse vs 4 rows/thread
__global__ __launch_bounds__(256) void gemm1_kernel(const float* __restrict__ x,
                                                    const float* __restrict__ W,
                                                    unsigned short* __restrict__ h1b) {
    __shared__ float xs[32][IN_DIM];  // 16 KB
    const int t = threadIdx.x;
    const int row0 = blockIdx.x * 32;
    for (int i = t * 4; i < 32 * IN_DIM; i += 1024) {
        int r = i >> 7, k = i & 127;
        int gr = row0 + r;
        float4 v = (gr < N_NODES) ? *(const float4*)&x[(size_t)gr * IN_DIM + k]
                                  : make_float4(0.f, 0.f, 0.f, 0.f);
        *(float4*)&xs[r][k] = v;
    }
    __syncthreads();
    const int cg = (t & 63) * 4;
    const int rg = (t >> 6) * 8;
    float acc[8][4] = {};
#pragma unroll 2
    for (int k = 0; k < IN_DIM; ++k) {
        const float4 w = *(const float4*)&W[k * C1 + cg];
#pragma unroll
        for (int r = 0; r < 8; ++r) {
            float xv = xs[rg + r][k];
            acc[r][0] += xv * w.x;
            acc[r][1] += xv * w.y;
            acc[r][2] += xv * w.z;
            acc[r][3] += xv * w.w;
        }
    }
#pragma unroll
    for (int r = 0; r < 8; ++r) {
        int gr = row0 + rg + r;
        if (gr < N_NODES) {
            ushort4 o;
            o.x = f2bf(acc[r][0]); o.y = f2bf(acc[r][1]);
            o.z = f2bf(acc[r][2]); o.w = f2bf(acc[r][3]);
            *(ushort4*)&h1b[(size_t)gr * C1 + cg] = o;
        }
    }
}

// ================================================================ alpha1 (bf16 h1)
__global__ __launch_bounds__(256) void alpha1_kernel(const unsigned short* __restrict__ h1b,
                                                     const float* __restrict__ a_src,
                                                     const float* __restrict__ a_dst,
                                                     float* __restrict__ as1,
                                                     float* __restrict__ ad1) {
    int i = blockIdx.x * 256 + threadIdx.x;
    if (i >= N_NODES * HEADS) return;
    int n = i >> 2, h = i & 3;
    const unsigned short* hp = h1b + (size_t)n * C1 + h * HID;
    const float* ap = a_src + h * HID;
    const float* bp = a_dst + h * HID;
    float s = 0.f, d = 0.f;
#pragma unroll
    for (int f = 0; f < HID; f += 4) {
        float4 hv = bf4_to_f4(*(const ushort4*)&hp[f]);
        float4 av = *(const float4*)&ap[f];
        float4 bv = *(const float4*)&bp[f];
        s += hv.x * av.x + hv.y * av.y + hv.z * av.z + hv.w * av.w;
        d += hv.x * bv.x + hv.y * bv.y + hv.z * bv.z + hv.w * bv.w;
    }
    as1[i] = s;
    ad1[i] = d;
}

// ================================================================ agg1 (bf16 gather)
__global__ __launch_bounds__(256) void agg1_kernel(const int* __restrict__ csr_src,
                                                   const int* __restrict__ row_start,
                                                   const unsigned short* __restrict__ h1b,
                                                   const float* __restrict__ as1,
                                                   const float* __restrict__ ad1,
                                                   const float* __restrict__ b1,
                                                   float* __restrict__ hp) {
    int n = (blockIdx.x * 256 + threadIdx.x) >> 6;  // dst node (1 wave each)
    if (n >= N_NODES) return;
    int lane = threadIdx.x & 63;
    int h = lane >> 4;
    int beg = row_start[n], end = row_start[n + 1];
    float ad = ad1[n * 4 + h];
    float4 acc = make_float4(0.f, 0.f, 0.f, 0.f);
    float sumw = 0.f;
    for (int i = beg; i < end; ++i) {
        int s = csr_src[i];
        float l = as1[s * 4 + h] + ad;
        l = l > 0.f ? l : NEG_SLOPE * l;
        float w = __expf(l);
        sumw += w;
        float4 hv = bf4_to_f4(*(const ushort4*)&h1b[(size_t)s * C1 + lane * 4]);
        acc.x += w * hv.x;
        acc.y += w * hv.y;
        acc.z += w * hv.z;
        acc.w += w * hv.w;
    }
    float inv = 1.f / (sumw + 1e-16f);
    const float4 bv = *(const float4*)&b1[lane * 4];
    float v0 = acc.x * inv + bv.x;
    float v1 = acc.y * inv + bv.y;
    float v2 = acc.z * inv + bv.z;
    float v3 = acc.w * inv + bv.w;
    v0 = v0 > 0.f ? v0 : __expf(v0) - 1.f;
    v1 = v1 > 0.f ? v1 : __expf(v1) - 1.f;
    v2 = v2 > 0.f ? v2 : __expf(v2) - 1.f;
    v3 = v3 > 0.f ? v3 : __expf(v3) - 1.f;
    *(float4*)&hp[(size_t)n * C1 + lane * 4] = make_float4(v0, v1, v2, v3);
}

// ================================================================ GEMM2
__global__ __launch_bounds__(256) void gemm2_kernel(const float* __restrict__ hp,
                                                    const float* __restrict__ W,
                                                    float* __restrict__ h2) {
    __shared__ float w2s[C1 * OUT_DIM];  // 32 KB
    __shared__ float xr[8][C1];          // 8 KB
    const int t = threadIdx.x;
    const int row0 = blockIdx.x * 8;
    for (int i = t; i < C1 * OUT_DIM; i += 256) w2s[i] = W[i];
    for (int i = t; i < 8 * C1; i += 256) {
        int r = i >> 8, k = i & 255;
        xr[r][k] = hp[(size_t)(row0 + r) * C1 + k];
    }
    __syncthreads();
    const int r = t >> 5, c = t & 31;
    float acc = 0.f;
#pragma unroll 8
    for (int k = 0; k < C1; ++k) acc += xr[r][k] * w2s[k * OUT_DIM + c];
    h2[(size_t)(row0 + r) * OUT_DIM + c] = acc;
}

// ================================================================ alpha2
__global__ __launch_bounds__(256) void alpha2_kernel(const float* __restrict__ h2,
                                                     const float* __restrict__ a_src,
                                                     const float* __restrict__ a_dst,
                                                     float* __restrict__ as2,
                                                     float* __restrict__ ad2) {
    int n = blockIdx.x * 256 + threadIdx.x;
    if (n >= N_NODES) return;
    const float* hp = h2 + (size_t)n * OUT_DIM;
    float s = 0.f, d = 0.f;
#pragma unroll
    for (int f = 0; f < OUT_DIM; f += 4) {
        float4 hv = *(const float4*)&hp[f];
        float4 av = *(const float4*)&a_src[f];
        float4 bv = *(const float4*)&a_dst[f];
        s += hv.x * av.x + hv.y * av.y + hv.z * av.z + hv.w * av.w;
        d += hv.x * bv.x + hv.y * bv.y + hv.z * bv.z + hv.w * bv.w;
    }
    as2[n] = s;
    ad2[n] = d;
}

// ================================================================ agg2: 8 dst/wave
__global__ __launch_bounds__(256) void agg2_kernel(const int* __restrict__ csr_src,
                                                   const int* __restrict__ row_start,
                                                   const float* __restrict__ h2,
                                                   const float* __restrict__ as2,
                                                   const float* __restrict__ ad2,
                                                   const float* __restrict__ b2,
                                                   float* __restrict__ out) {
    int wave = (blockIdx.x * 256 + threadIdx.x) >> 6;
    int lane = threadIdx.x & 63;
    int seg = lane >> 3;
    int sub = lane & 7;
    int n = wave * 8 + seg;
    if (n >= N_NODES) return;
    int beg = row_start[n], end = row_start[n + 1];
    float ad = ad2[n];
    float4 acc = make_float4(0.f, 0.f, 0.f, 0.f);
    float sumw = 0.f;
    for (int i = beg; i < end; ++i) {
        int s = csr_src[i];
        float l = as2[s] + ad;
        l = l > 0.f ? l : NEG_SLOPE * l;
        float w = __expf(l);
        sumw += w;
        float4 hv = *(const float4*)&h2[(size_t)s * OUT_DIM + sub * 4];
        acc.x += w * hv.x;
        acc.y += w * hv.y;
        acc.z += w * hv.z;
        acc.w += w * hv.w;
    }
    float inv = 1.f / (sumw + 1e-16f);
    const float4 bv = *(const float4*)&b2[sub * 4];
    *(float4*)&out[(size_t)n * OUT_DIM + sub * 4] =
        make_float4(acc.x * inv + bv.x, acc.y * inv + bv.y,
                    acc.z * inv + bv.z, acc.w * inv + bv.w);
}

extern "C" void kernel_launch(void* const* d_in, const int* in_sizes, int n_in,
                              void* d_out, int out_size, void* d_ws, size_t ws_size,
                              hipStream_t stream) {
    const float* x      = (const float*)d_in[0];
    const int*   ei     = (const int*)d_in[1];
    const float* W1     = (const float*)d_in[2];
    const float* a_src1 = (const float*)d_in[3];
    const float* a_dst1 = (const float*)d_in[4];
    const float* b1     = (const float*)d_in[5];
    const float* W2     = (const float*)d_in[6];
    const float* a_src2 = (const float*)d_in[7];
    const float* a_dst2 = (const float*)d_in[8];
    const float* b2     = (const float*)d_in[9];
    float* out = (float*)d_out;

    // workspace layout
    unsigned short* h1b = (unsigned short*)d_ws;        // 12.8M bf16 = 25.6 MB
    float* hp     = (float*)(h1b + 12800000);           // 12.8M fp32
    float* h2     = hp + 12800000;                      // 1.6M
    float* as1    = h2 + 1600000;                       // 200k
    float* ad1    = as1 + 200000;                       // 200k
    float* as2    = ad1 + 200000;                       // 50k
    float* ad2    = as2 + 50000;                        // 50k
    int* csr_src  = (int*)(ad2 + 50000);                // 850k
    int* row_start= csr_src + E_TOT;                    // 50001
    int* deg      = row_start + (N_NODES + 1);          // 50k
    int* cursor   = deg + N_NODES;                      // 50k
    int* incl     = cursor + N_NODES;                   // 50k
    int* blocksum = incl + N_NODES;                     // 256
    int* blockoff = blocksum + 256;                     // 256

    hipMemsetAsync(deg, 0, (size_t)N_NODES * 4, stream);
    hipMemsetAsync(cursor, 0, (size_t)N_NODES * 4, stream);

    const int EB = (E_TOT + 255) / 256;
    deg_kernel<<<EB, 256, 0, stream>>>(ei, deg);
    scanA_kernel<<<SCAN_NBLK, 256, 0, stream>>>(deg, incl, blocksum);
    scanB_kernel<<<1, 256, 0, stream>>>(blocksum, blockoff);
    scanC_kernel<<<SCAN_NBLK, 256, 0, stream>>>(deg, incl, blockoff, row_start);
    scatter_kernel<<<EB, 256, 0, stream>>>(ei, row_start, cursor, csr_src);

    // layer 1
    gemm1_kernel<<<(N_NODES + 31) / 32, 256, 0, stream>>>(x, W1, h1b);
    alpha1_kernel<<<(N_NODES * HEADS + 255) / 256, 256, 0, stream>>>(h1b, a_src1, a_dst1, as1, ad1);
    agg1_kernel<<<(N_NODES * 64 + 255) / 256, 256, 0, stream>>>(csr_src, row_start, h1b, as1, ad1, b1, hp);

    // layer 2
    gemm2_kernel<<<N_NODES / 8, 256, 0, stream>>>(hp, W2, h2);
    alpha2_kernel<<<(N_NODES + 255) / 256, 256, 0, stream>>>(h2, a_src2, a_dst2, as2, ad2);
    agg2_kernel<<<(((N_NODES + 7) / 8) * 64 + 255) / 256, 256, 0, stream>>>(csr_src, row_start, h2, as2, ad2, b2, out);
}

// Round 4
// 333.785 us; speedup vs baseline: 10.8583x; 1.2462x over previous
//
#include <hip/hip_runtime.h>
#include <hip/hip_bf16.h>

#define N_NODES 50000
#define N_EDGES 800000
#define E_TOT   850000   // edges + self loops
#define IN_DIM  128
#define C1      256      // HEADS*HID
#define HEADS   4
#define HID     64
#define OUT_DIM 32
#define NEG_SLOPE 0.2f
#define SCAN_NBLK 196    // ceil(50000/256)

typedef __attribute__((ext_vector_type(8))) short bf16x8;
typedef __attribute__((ext_vector_type(4))) float f32x4;

__device__ __forceinline__ void edge_sd(const int* __restrict__ ei, int e, int& s, int& d) {
    if (e < N_EDGES) { s = ei[e]; d = ei[N_EDGES + e]; }
    else             { s = d = e - N_EDGES; }
}

__device__ __forceinline__ unsigned short f2bf(float f) {
    unsigned u = __float_as_uint(f);
    u += 0x7fffu + ((u >> 16) & 1u);   // RNE
    return (unsigned short)(u >> 16);
}
__device__ __forceinline__ float bf2f(unsigned short u) {
    return __uint_as_float(((unsigned)u) << 16);
}
__device__ __forceinline__ float4 bf4_to_f4(ushort4 v) {
    return make_float4(bf2f(v.x), bf2f(v.y), bf2f(v.z), bf2f(v.w));
}

// ================================================================ CSR build
__global__ __launch_bounds__(256) void deg_kernel(const int* __restrict__ ei,
                                                  int* __restrict__ deg) {
    int e = blockIdx.x * 256 + threadIdx.x;
    if (e >= E_TOT) return;
    int s, d; edge_sd(ei, e, s, d);
    atomicAdd(&deg[d], 1);
}

__global__ __launch_bounds__(256) void scanA_kernel(const int* __restrict__ deg,
                                                    int* __restrict__ incl,
                                                    int* __restrict__ blocksum) {
    __shared__ int sm[256];
    int t = threadIdx.x, idx = blockIdx.x * 256 + t;
    int v = (idx < N_NODES) ? deg[idx] : 0;
    sm[t] = v; __syncthreads();
#pragma unroll
    for (int off = 1; off < 256; off <<= 1) {
        int u = (t >= off) ? sm[t - off] : 0;
        __syncthreads();
        sm[t] += u;
        __syncthreads();
    }
    if (idx < N_NODES) incl[idx] = sm[t];
    if (t == 255) blocksum[blockIdx.x] = sm[t];
}

// scanC with fused block-offset computation (replaces old scanB+scanC)
__global__ __launch_bounds__(256) void scanC_kernel(const int* __restrict__ deg,
                                                    const int* __restrict__ incl,
                                                    const int* __restrict__ blocksum,
                                                    int* __restrict__ row_start) {
    __shared__ int wsum[4];
    int t = threadIdx.x;
    int v = (t < (int)blockIdx.x) ? blocksum[t] : 0;   // blockIdx.x <= 195
#pragma unroll
    for (int m = 32; m >= 1; m >>= 1) v += __shfl_xor(v, m, 64);
    if ((t & 63) == 0) wsum[t >> 6] = v;
    __syncthreads();
    int off = wsum[0] + wsum[1] + wsum[2] + wsum[3];
    int idx = blockIdx.x * 256 + t;
    if (idx >= N_NODES) return;
    row_start[idx] = off + incl[idx] - deg[idx];
    if (idx == N_NODES - 1) row_start[N_NODES] = off + incl[idx];  // == E_TOT
}

__global__ __launch_bounds__(256) void scatter_kernel(const int* __restrict__ ei,
                                                      const int* __restrict__ row_start,
                                                      int* __restrict__ cursor,
                                                      int* __restrict__ csr_src) {
    int e = blockIdx.x * 256 + threadIdx.x;
    if (e >= E_TOT) return;
    int s, d; edge_sd(ei, e, s, d);
    int pos = atomicAdd(&cursor[d], 1);
    csr_src[row_start[d] + pos] = s;
}

// ================================================================ pack W1 into B-fragment order (bf16)
// Bp[((K0*256 + n)*4 + q)*8 + j] = bf16(W1[(K0*32 + q*8 + j)*256 + n])
__global__ __launch_bounds__(256) void packW1_kernel(const float* __restrict__ W,
                                                     unsigned short* __restrict__ Bp) {
    int tid = blockIdx.x * 256 + threadIdx.x;
    if (tid >= IN_DIM * C1) return;
    int j = tid & 7, q = (tid >> 3) & 3, n = (tid >> 5) & 255, K0 = tid >> 13;
    int k = K0 * 32 + q * 8 + j;
    Bp[tid] = f2bf(W[k * C1 + n]);
}

// ================================================================ GEMM1 (MFMA bf16) + fused alpha1
// h1b[50000,256](bf16) = x @ W1; as1/ad1 from fp32 accumulators via quad-reduce.
// block = 16 rows (exact: 50000 = 16*3125); wave w = head w = cols [w*64, w*64+64)
__global__ __launch_bounds__(256) void gemm1_kernel(const float* __restrict__ x,
                                                    const unsigned short* __restrict__ Bp,
                                                    const float* __restrict__ a_src1,
                                                    const float* __restrict__ a_dst1,
                                                    unsigned short* __restrict__ h1b,
                                                    float* __restrict__ as1,
                                                    float* __restrict__ ad1) {
    __shared__ unsigned short xs[16][136];  // +8 pad -> 2-way LDS aliasing (free)
    const int t = threadIdx.x;
    const int row0 = blockIdx.x * 16;
    {   // stage A tile: 16 x 128 fp32 -> bf16; 8 elems/thread
        int r = t >> 4, k0 = (t & 15) * 8;
        const float* xp = &x[(size_t)(row0 + r) * IN_DIM + k0];
        float4 v0 = *(const float4*)xp;
        float4 v1 = *(const float4*)(xp + 4);
        ushort4 o0, o1;
        o0.x = f2bf(v0.x); o0.y = f2bf(v0.y); o0.z = f2bf(v0.z); o0.w = f2bf(v0.w);
        o1.x = f2bf(v1.x); o1.y = f2bf(v1.y); o1.z = f2bf(v1.z); o1.w = f2bf(v1.w);
        *(ushort4*)&xs[r][k0] = o0;
        *(ushort4*)&xs[r][k0 + 4] = o1;
    }
    __syncthreads();
    const int wave = t >> 6;         // head index
    const int lane = t & 63;
    const int nl = lane & 15, q = lane >> 4;
    f32x4 acc[4];
    f32x4 z = {0.f, 0.f, 0.f, 0.f};
    acc[0] = z; acc[1] = z; acc[2] = z; acc[3] = z;
#pragma unroll
    for (int K0 = 0; K0 < 4; ++K0) {
        bf16x8 af = *(const bf16x8*)&xs[nl][K0 * 32 + q * 8];
#pragma unroll
        for (int sub = 0; sub < 4; ++sub) {
            int n = wave * 64 + sub * 16 + nl;
            bf16x8 bfv = *(const bf16x8*)&Bp[((size_t)(K0 * 256 + n) * 4 + q) * 8];
            acc[sub] = __builtin_amdgcn_mfma_f32_16x16x32_bf16(af, bfv, acc[sub], 0, 0, 0);
        }
    }
    // epilogue: store bf16 h1 + fused alpha1 (quad-reduce over nl)
    float asv[4], adv[4];
#pragma unroll
    for (int sub = 0; sub < 4; ++sub) {
        asv[sub] = a_src1[wave * 64 + sub * 16 + nl];
        adv[sub] = a_dst1[wave * 64 + sub * 16 + nl];
    }
#pragma unroll
    for (int r = 0; r < 4; ++r) {
        int gr = row0 + q * 4 + r;   // C/D: row = quad*4 + reg, col = lane&15
        float ps = 0.f, pd = 0.f;
#pragma unroll
        for (int sub = 0; sub < 4; ++sub) {
            float v = acc[sub][r];
            h1b[(size_t)gr * C1 + wave * 64 + sub * 16 + nl] = f2bf(v);
            ps += v * asv[sub];
            pd += v * adv[sub];
        }
#pragma unroll
        for (int m = 8; m >= 1; m >>= 1) {
            ps += __shfl_xor(ps, m, 16);
            pd += __shfl_xor(pd, m, 16);
        }
        if (nl == 0) {
            as1[gr * 4 + wave] = ps;
            ad1[gr * 4 + wave] = pd;
        }
    }
}

// ================================================================ agg1 (bf16 gather, 4x unrolled)
__global__ __launch_bounds__(256) void agg1_kernel(const int* __restrict__ csr_src,
                                                   const int* __restrict__ row_start,
                                                   const unsigned short* __restrict__ h1b,
                                                   const float* __restrict__ as1,
                                                   const float* __restrict__ ad1,
                                                   const float* __restrict__ b1,
                                                   float* __restrict__ hp) {
    int n = (blockIdx.x * 256 + threadIdx.x) >> 6;  // 1 wave per dst
    if (n >= N_NODES) return;
    int lane = threadIdx.x & 63;
    int h = lane >> 4;
    int beg = row_start[n], end = row_start[n + 1];
    float ad = ad1[n * 4 + h];
    float4 acc = make_float4(0.f, 0.f, 0.f, 0.f);
    float sumw = 0.f;
    int i = beg;
    for (; i + 4 <= end; i += 4) {
        int s0 = csr_src[i], s1 = csr_src[i + 1], s2 = csr_src[i + 2], s3 = csr_src[i + 3];
        float a0 = as1[s0 * 4 + h], a1 = as1[s1 * 4 + h];
        float a2 = as1[s2 * 4 + h], a3 = as1[s3 * 4 + h];
        ushort4 r0 = *(const ushort4*)&h1b[(size_t)s0 * C1 + lane * 4];
        ushort4 r1 = *(const ushort4*)&h1b[(size_t)s1 * C1 + lane * 4];
        ushort4 r2 = *(const ushort4*)&h1b[(size_t)s2 * C1 + lane * 4];
        ushort4 r3 = *(const ushort4*)&h1b[(size_t)s3 * C1 + lane * 4];
        float l0 = a0 + ad, l1 = a1 + ad, l2 = a2 + ad, l3 = a3 + ad;
        l0 = l0 > 0.f ? l0 : NEG_SLOPE * l0;
        l1 = l1 > 0.f ? l1 : NEG_SLOPE * l1;
        l2 = l2 > 0.f ? l2 : NEG_SLOPE * l2;
        l3 = l3 > 0.f ? l3 : NEG_SLOPE * l3;
        float w0 = __expf(l0), w1 = __expf(l1), w2 = __expf(l2), w3 = __expf(l3);
        sumw += (w0 + w1) + (w2 + w3);
        float4 f0 = bf4_to_f4(r0), f1 = bf4_to_f4(r1);
        float4 f2 = bf4_to_f4(r2), f3 = bf4_to_f4(r3);
        acc.x += w0 * f0.x + w1 * f1.x + w2 * f2.x + w3 * f3.x;
        acc.y += w0 * f0.y + w1 * f1.y + w2 * f2.y + w3 * f3.y;
        acc.z += w0 * f0.z + w1 * f1.z + w2 * f2.z + w3 * f3.z;
        acc.w += w0 * f0.w + w1 * f1.w + w2 * f2.w + w3 * f3.w;
    }
    for (; i < end; ++i) {
        int s = csr_src[i];
        float l = as1[s * 4 + h] + ad;
        l = l > 0.f ? l : NEG_SLOPE * l;
        float w = __expf(l);
        sumw += w;
        float4 hv = bf4_to_f4(*(const ushort4*)&h1b[(size_t)s * C1 + lane * 4]);
        acc.x += w * hv.x; acc.y += w * hv.y; acc.z += w * hv.z; acc.w += w * hv.w;
    }
    float inv = 1.f / (sumw + 1e-16f);
    const float4 bv = *(const float4*)&b1[lane * 4];
    float v0 = acc.x * inv + bv.x;
    float v1 = acc.y * inv + bv.y;
    float v2 = acc.z * inv + bv.z;
    float v3 = acc.w * inv + bv.w;
    v0 = v0 > 0.f ? v0 : __expf(v0) - 1.f;
    v1 = v1 > 0.f ? v1 : __expf(v1) - 1.f;
    v2 = v2 > 0.f ? v2 : __expf(v2) - 1.f;
    v3 = v3 > 0.f ? v3 : __expf(v3) - 1.f;
    *(float4*)&hp[(size_t)n * C1 + lane * 4] = make_float4(v0, v1, v2, v3);
}

// ================================================================ GEMM2 + fused alpha2
__global__ __launch_bounds__(256) void gemm2_kernel(const float* __restrict__ hp,
                                                    const float* __restrict__ W,
                                                    const float* __restrict__ a_src2,
                                                    const float* __restrict__ a_dst2,
                                                    float* __restrict__ h2,
                                                    float* __restrict__ as2,
                                                    float* __restrict__ ad2) {
    __shared__ float w2s[C1 * OUT_DIM];  // 32 KB
    __shared__ float xr[8][C1];          // 8 KB
    const int t = threadIdx.x;
    const int row0 = blockIdx.x * 8;
    for (int i = t; i < C1 * OUT_DIM; i += 256) w2s[i] = W[i];
    for (int i = t; i < 8 * C1; i += 256) {
        int r = i >> 8, k = i & 255;
        xr[r][k] = hp[(size_t)(row0 + r) * C1 + k];
    }
    __syncthreads();
    const int r = t >> 5, c = t & 31;
    float acc = 0.f;
#pragma unroll 8
    for (int k = 0; k < C1; ++k) acc += xr[r][k] * w2s[k * OUT_DIM + c];
    h2[(size_t)(row0 + r) * OUT_DIM + c] = acc;
    // fused alpha2: reduce over 32 cols (one row per 32-lane half-wave)
    float ps = acc * a_src2[c];
    float pd = acc * a_dst2[c];
#pragma unroll
    for (int m = 16; m >= 1; m >>= 1) {
        ps += __shfl_xor(ps, m, 32);
        pd += __shfl_xor(pd, m, 32);
    }
    if (c == 0) {
        as2[row0 + r] = ps;
        ad2[row0 + r] = pd;
    }
}

// ================================================================ agg2: 8 dst/wave, 4x unrolled
__global__ __launch_bounds__(256) void agg2_kernel(const int* __restrict__ csr_src,
                                                   const int* __restrict__ row_start,
                                                   const float* __restrict__ h2,
                                                   const float* __restrict__ as2,
                                                   const float* __restrict__ ad2,
                                                   const float* __restrict__ b2,
                                                   float* __restrict__ out) {
    int wave = (blockIdx.x * 256 + threadIdx.x) >> 6;
    int lane = threadIdx.x & 63;
    int seg = lane >> 3;
    int sub = lane & 7;
    int n = wave * 8 + seg;
    if (n >= N_NODES) return;
    int beg = row_start[n], end = row_start[n + 1];
    float ad = ad2[n];
    float4 acc = make_float4(0.f, 0.f, 0.f, 0.f);
    float sumw = 0.f;
    int i = beg;
    for (; i + 4 <= end; i += 4) {
        int s0 = csr_src[i], s1 = csr_src[i + 1], s2 = csr_src[i + 2], s3 = csr_src[i + 3];
        float a0 = as2[s0], a1 = as2[s1], a2 = as2[s2], a3 = as2[s3];
        float4 f0 = *(const float4*)&h2[(size_t)s0 * OUT_DIM + sub * 4];
        float4 f1 = *(const float4*)&h2[(size_t)s1 * OUT_DIM + sub * 4];
        float4 f2 = *(const float4*)&h2[(size_t)s2 * OUT_DIM + sub * 4];
        float4 f3 = *(const float4*)&h2[(size_t)s3 * OUT_DIM + sub * 4];
        float l0 = a0 + ad, l1 = a1 + ad, l2 = a2 + ad, l3 = a3 + ad;
        l0 = l0 > 0.f ? l0 : NEG_SLOPE * l0;
        l1 = l1 > 0.f ? l1 : NEG_SLOPE * l1;
        l2 = l2 > 0.f ? l2 : NEG_SLOPE * l2;
        l3 = l3 > 0.f ? l3 : NEG_SLOPE * l3;
        float w0 = __expf(l0), w1 = __expf(l1), w2 = __expf(l2), w3 = __expf(l3);
        sumw += (w0 + w1) + (w2 + w3);
        acc.x += w0 * f0.x + w1 * f1.x + w2 * f2.x + w3 * f3.x;
        acc.y += w0 * f0.y + w1 * f1.y + w2 * f2.y + w3 * f3.y;
        acc.z += w0 * f0.z + w1 * f1.z + w2 * f2.z + w3 * f3.z;
        acc.w += w0 * f0.w + w1 * f1.w + w2 * f2.w + w3 * f3.w;
    }
    for (; i < end; ++i) {
        int s = csr_src[i];
        float l = as2[s] + ad;
        l = l > 0.f ? l : NEG_SLOPE * l;
        float w = __expf(l);
        sumw += w;
        float4 hv = *(const float4*)&h2[(size_t)s * OUT_DIM + sub * 4];
        acc.x += w * hv.x; acc.y += w * hv.y; acc.z += w * hv.z; acc.w += w * hv.w;
    }
    float inv = 1.f / (sumw + 1e-16f);
    const float4 bv = *(const float4*)&b2[sub * 4];
    *(float4*)&out[(size_t)n * OUT_DIM + sub * 4] =
        make_float4(acc.x * inv + bv.x, acc.y * inv + bv.y,
                    acc.z * inv + bv.z, acc.w * inv + bv.w);
}

extern "C" void kernel_launch(void* const* d_in, const int* in_sizes, int n_in,
                              void* d_out, int out_size, void* d_ws, size_t ws_size,
                              hipStream_t stream) {
    const float* x      = (const float*)d_in[0];
    const int*   ei     = (const int*)d_in[1];
    const float* W1     = (const float*)d_in[2];
    const float* a_src1 = (const float*)d_in[3];
    const float* a_dst1 = (const float*)d_in[4];
    const float* b1     = (const float*)d_in[5];
    const float* W2     = (const float*)d_in[6];
    const float* a_src2 = (const float*)d_in[7];
    const float* a_dst2 = (const float*)d_in[8];
    const float* b2     = (const float*)d_in[9];
    float* out = (float*)d_out;

    // workspace layout
    unsigned short* h1b = (unsigned short*)d_ws;        // 12.8M bf16
    unsigned short* Bp  = h1b + 12800000;               // 32768 bf16
    float* hp     = (float*)(Bp + 32768);               // 12.8M fp32
    float* h2     = hp + 12800000;                      // 1.6M
    float* as1    = h2 + 1600000;                       // 200k
    float* ad1    = as1 + 200000;                       // 200k
    float* as2    = ad1 + 200000;                       // 50k
    float* ad2    = as2 + 50000;                        // 50k
    int* csr_src  = (int*)(ad2 + 50000);                // 850k
    int* row_start= csr_src + E_TOT;                    // 50001
    int* deg      = row_start + (N_NODES + 1);          // 50k  \ adjacent:
    int* cursor   = deg + N_NODES;                      // 50k  / single memset
    int* incl     = cursor + N_NODES;                   // 50k
    int* blocksum = incl + N_NODES;                     // 256

    hipMemsetAsync(deg, 0, (size_t)(2 * N_NODES) * 4, stream);  // deg + cursor

    const int EB = (E_TOT + 255) / 256;
    packW1_kernel<<<(IN_DIM * C1 + 255) / 256, 256, 0, stream>>>(W1, Bp);
    deg_kernel<<<EB, 256, 0, stream>>>(ei, deg);
    scanA_kernel<<<SCAN_NBLK, 256, 0, stream>>>(deg, incl, blocksum);
    scanC_kernel<<<SCAN_NBLK, 256, 0, stream>>>(deg, incl, blocksum, row_start);
    scatter_kernel<<<EB, 256, 0, stream>>>(ei, row_start, cursor, csr_src);

    // layer 1
    gemm1_kernel<<<N_NODES / 16, 256, 0, stream>>>(x, Bp, a_src1, a_dst1, h1b, as1, ad1);
    agg1_kernel<<<(N_NODES * 64 + 255) / 256, 256, 0, stream>>>(csr_src, row_start, h1b, as1, ad1, b1, hp);

    // layer 2
    gemm2_kernel<<<N_NODES / 8, 256, 0, stream>>>(hp, W2, a_src2, a_dst2, h2, as2, ad2);
    agg2_kernel<<<(((N_NODES + 7) / 8) * 64 + 255) / 256, 256, 0, stream>>>(csr_src, row_start, h2, as2, ad2, b2, out);
}

// Round 5
// 311.896 us; speedup vs baseline: 11.6204x; 1.0702x over previous
//
#include <hip/hip_runtime.h>
#include <hip/hip_bf16.h>

#define N_NODES 50000
#define N_EDGES 800000
#define E_TOT   850000   // edges + self loops
#define IN_DIM  128
#define C1      256      // HEADS*HID
#define HEADS   4
#define HID     64
#define OUT_DIM 32
#define NEG_SLOPE 0.2f
#define SCAN_NBLK 196    // ceil(50000/256)

typedef __attribute__((ext_vector_type(8))) short bf16x8;
typedef __attribute__((ext_vector_type(8))) unsigned short u16x8;
typedef __attribute__((ext_vector_type(4))) float f32x4;

__device__ __forceinline__ void edge_sd(const int* __restrict__ ei, int e, int& s, int& d) {
    if (e < N_EDGES) { s = ei[e]; d = ei[N_EDGES + e]; }
    else             { s = d = e - N_EDGES; }
}

__device__ __forceinline__ unsigned short f2bf(float f) {
    unsigned u = __float_as_uint(f);
    u += 0x7fffu + ((u >> 16) & 1u);   // RNE
    return (unsigned short)(u >> 16);
}
__device__ __forceinline__ float bf2f(unsigned short u) {
    return __uint_as_float(((unsigned)u) << 16);
}

// ================================================================ CSR build
__global__ __launch_bounds__(256) void deg_kernel(const int* __restrict__ ei,
                                                  int* __restrict__ deg) {
    int e = blockIdx.x * 256 + threadIdx.x;
    if (e >= E_TOT) return;
    int s, d; edge_sd(ei, e, s, d);
    atomicAdd(&deg[d], 1);
}

__global__ __launch_bounds__(256) void scanA_kernel(const int* __restrict__ deg,
                                                    int* __restrict__ incl,
                                                    int* __restrict__ blocksum) {
    __shared__ int sm[256];
    int t = threadIdx.x, idx = blockIdx.x * 256 + t;
    int v = (idx < N_NODES) ? deg[idx] : 0;
    sm[t] = v; __syncthreads();
#pragma unroll
    for (int off = 1; off < 256; off <<= 1) {
        int u = (t >= off) ? sm[t - off] : 0;
        __syncthreads();
        sm[t] += u;
        __syncthreads();
    }
    if (idx < N_NODES) incl[idx] = sm[t];
    if (t == 255) blocksum[blockIdx.x] = sm[t];
}

__global__ __launch_bounds__(256) void scanC_kernel(const int* __restrict__ deg,
                                                    const int* __restrict__ incl,
                                                    const int* __restrict__ blocksum,
                                                    int* __restrict__ row_start) {
    __shared__ int wsum[4];
    int t = threadIdx.x;
    int v = (t < (int)blockIdx.x) ? blocksum[t] : 0;   // blockIdx.x <= 195
#pragma unroll
    for (int m = 32; m >= 1; m >>= 1) v += __shfl_xor(v, m, 64);
    if ((t & 63) == 0) wsum[t >> 6] = v;
    __syncthreads();
    int off = wsum[0] + wsum[1] + wsum[2] + wsum[3];
    int idx = blockIdx.x * 256 + t;
    if (idx >= N_NODES) return;
    row_start[idx] = off + incl[idx] - deg[idx];
    if (idx == N_NODES - 1) row_start[N_NODES] = off + incl[idx];  // == E_TOT
}

__global__ __launch_bounds__(256) void scatter_kernel(const int* __restrict__ ei,
                                                      const int* __restrict__ row_start,
                                                      int* __restrict__ cursor,
                                                      int* __restrict__ csr_src) {
    int e = blockIdx.x * 256 + threadIdx.x;
    if (e >= E_TOT) return;
    int s, d; edge_sd(ei, e, s, d);
    int pos = atomicAdd(&cursor[d], 1);
    csr_src[row_start[d] + pos] = s;
}

// ================================================================ setup: pack W1 + W2 into B-fragment order (bf16)
// Bp1[((K0*256 + n)*4 + q)*8 + j] = bf16(W1[(K0*32 + q*8 + j)*256 + n])  (32768 elems)
// Bp2[((K0*32  + n)*4 + q)*8 + j] = bf16(W2[(K0*32 + q*8 + j)*32  + n])  (8192 elems)
__global__ __launch_bounds__(256) void setup_kernel(const float* __restrict__ W1,
                                                    const float* __restrict__ W2,
                                                    unsigned short* __restrict__ Bp1,
                                                    unsigned short* __restrict__ Bp2) {
    int tid = blockIdx.x * 256 + threadIdx.x;
    if (tid < IN_DIM * C1) {
        int j = tid & 7, q = (tid >> 3) & 3, n = (tid >> 5) & 255, K0 = tid >> 13;
        int k = K0 * 32 + q * 8 + j;
        Bp1[tid] = f2bf(W1[k * C1 + n]);
    } else if (tid < IN_DIM * C1 + C1 * OUT_DIM) {
        int t2 = tid - IN_DIM * C1;
        int j = t2 & 7, q = (t2 >> 3) & 3, n = (t2 >> 5) & 31, K0 = t2 >> 10;
        int k = K0 * 32 + q * 8 + j;
        Bp2[t2] = f2bf(W2[k * OUT_DIM + n]);
    }
}

// ================================================================ GEMM1 (MFMA bf16) + fused alpha1
__global__ __launch_bounds__(256) void gemm1_kernel(const float* __restrict__ x,
                                                    const unsigned short* __restrict__ Bp,
                                                    const float* __restrict__ a_src1,
                                                    const float* __restrict__ a_dst1,
                                                    unsigned short* __restrict__ h1b,
                                                    float* __restrict__ as1,
                                                    float* __restrict__ ad1) {
    __shared__ unsigned short xs[16][136];  // +8 pad -> 2-way LDS aliasing (free)
    const int t = threadIdx.x;
    const int row0 = blockIdx.x * 16;
    {   // stage A tile: 16 x 128 fp32 -> bf16; 8 elems/thread
        int r = t >> 4, k0 = (t & 15) * 8;
        const float* xp = &x[(size_t)(row0 + r) * IN_DIM + k0];
        float4 v0 = *(const float4*)xp;
        float4 v1 = *(const float4*)(xp + 4);
        ushort4 o0, o1;
        o0.x = f2bf(v0.x); o0.y = f2bf(v0.y); o0.z = f2bf(v0.z); o0.w = f2bf(v0.w);
        o1.x = f2bf(v1.x); o1.y = f2bf(v1.y); o1.z = f2bf(v1.z); o1.w = f2bf(v1.w);
        *(ushort4*)&xs[r][k0] = o0;
        *(ushort4*)&xs[r][k0 + 4] = o1;
    }
    __syncthreads();
    const int wave = t >> 6;         // head index
    const int lane = t & 63;
    const int nl = lane & 15, q = lane >> 4;
    f32x4 acc[4];
    f32x4 z = {0.f, 0.f, 0.f, 0.f};
    acc[0] = z; acc[1] = z; acc[2] = z; acc[3] = z;
#pragma unroll
    for (int K0 = 0; K0 < 4; ++K0) {
        bf16x8 af = *(const bf16x8*)&xs[nl][K0 * 32 + q * 8];
#pragma unroll
        for (int sub = 0; sub < 4; ++sub) {
            int n = wave * 64 + sub * 16 + nl;
            bf16x8 bfv = *(const bf16x8*)&Bp[((size_t)(K0 * 256 + n) * 4 + q) * 8];
            acc[sub] = __builtin_amdgcn_mfma_f32_16x16x32_bf16(af, bfv, acc[sub], 0, 0, 0);
        }
    }
    float asv[4], adv[4];
#pragma unroll
    for (int sub = 0; sub < 4; ++sub) {
        asv[sub] = a_src1[wave * 64 + sub * 16 + nl];
        adv[sub] = a_dst1[wave * 64 + sub * 16 + nl];
    }
#pragma unroll
    for (int r = 0; r < 4; ++r) {
        int gr = row0 + q * 4 + r;   // C/D: row = quad*4 + reg, col = lane&15
        float ps = 0.f, pd = 0.f;
#pragma unroll
        for (int sub = 0; sub < 4; ++sub) {
            float v = acc[sub][r];
            h1b[(size_t)gr * C1 + wave * 64 + sub * 16 + nl] = f2bf(v);
            ps += v * asv[sub];
            pd += v * adv[sub];
        }
#pragma unroll
        for (int m = 8; m >= 1; m >>= 1) {
            ps += __shfl_xor(ps, m, 16);
            pd += __shfl_xor(pd, m, 16);
        }
        if (nl == 0) {
            as1[gr * 4 + wave] = ps;
            ad1[gr * 4 + wave] = pd;
        }
    }
}

// ================================================================ agg1: 1 wave/dst, 2 edges x 32 lanes x 16B, unroll 4
__global__ __launch_bounds__(256) void agg1_kernel(const int* __restrict__ csr_src,
                                                   const int* __restrict__ row_start,
                                                   const unsigned short* __restrict__ h1b,
                                                   const float* __restrict__ as1,
                                                   const float* __restrict__ ad1,
                                                   const float* __restrict__ b1,
                                                   unsigned short* __restrict__ hpb) {
    int n = (blockIdx.x * 256 + threadIdx.x) >> 6;
    if (n >= N_NODES) return;
    int lane = threadIdx.x & 63;
    int e2 = lane >> 5;          // which of 2 edges per iter-slot
    int c  = lane & 31;          // elem chunk: covers [c*8, c*8+8)
    int h  = c >> 3;             // head
    int beg = row_start[n], end = row_start[n + 1];
    float ad = ad1[n * 4 + h];
    float acc[8] = {0.f, 0.f, 0.f, 0.f, 0.f, 0.f, 0.f, 0.f};
    float sumw = 0.f;
    for (int i = beg; i < end; i += 8) {
#pragma unroll
        for (int u = 0; u < 4; ++u) {
            int idx = i + e2 + 2 * u;
            bool valid = idx < end;
            int ic = valid ? idx : beg;       // safe slot (deg >= 1 via self-loop)
            int s = csr_src[ic];
            float l = as1[s * 4 + h] + ad;
            l = l > 0.f ? l : NEG_SLOPE * l;
            float w = valid ? __expf(l) : 0.f;
            sumw += w;
            u16x8 rv = *(const u16x8*)&h1b[(size_t)s * C1 + c * 8];
#pragma unroll
            for (int k = 0; k < 8; ++k) acc[k] += w * bf2f(rv[k]);
        }
    }
    // combine the two edge-halves
    sumw += __shfl_xor(sumw, 32, 64);
#pragma unroll
    for (int k = 0; k < 8; ++k) acc[k] += __shfl_xor(acc[k], 32, 64);
    if (e2 == 0) {
        float inv = 1.f / (sumw + 1e-16f);
        const float4 b0 = *(const float4*)&b1[c * 8];
        const float4 b4 = *(const float4*)&b1[c * 8 + 4];
        float bb[8] = {b0.x, b0.y, b0.z, b0.w, b4.x, b4.y, b4.z, b4.w};
        u16x8 o;
#pragma unroll
        for (int k = 0; k < 8; ++k) {
            float v = acc[k] * inv + bb[k];
            v = v > 0.f ? v : __expf(v) - 1.f;
            o[k] = f2bf(v);
        }
        *(u16x8*)&hpb[(size_t)n * C1 + c * 8] = o;
    }
}

// ================================================================ GEMM2 (MFMA bf16) + fused alpha2
// h2[50000,32] = hp(bf16) @ W2; block = 64 rows (4 waves x 16)
__global__ __launch_bounds__(256) void gemm2_kernel(const unsigned short* __restrict__ hpb,
                                                    const unsigned short* __restrict__ Bp2,
                                                    const float* __restrict__ a_src2,
                                                    const float* __restrict__ a_dst2,
                                                    float* __restrict__ h2,
                                                    float* __restrict__ as2,
                                                    float* __restrict__ ad2) {
    __shared__ unsigned short xs[64][264];  // stride 264 shorts -> 2-way bank aliasing (free)
    const int t = threadIdx.x;
    const int row0 = blockIdx.x * 64;
    for (int idx = t; idx < 2048; idx += 256) {  // 64 rows x 32 chunks of 8
        int r = idx >> 5, ch = (idx & 31) * 8;
        int gr = row0 + r;
        u16x8 v = {0, 0, 0, 0, 0, 0, 0, 0};
        if (gr < N_NODES) v = *(const u16x8*)&hpb[(size_t)gr * C1 + ch];
        *(u16x8*)&xs[r][ch] = v;
    }
    __syncthreads();
    const int wave = t >> 6, lane = t & 63;
    const int nl = lane & 15, q = lane >> 4;
    f32x4 acc0 = {0.f, 0.f, 0.f, 0.f}, acc1 = {0.f, 0.f, 0.f, 0.f};
#pragma unroll
    for (int K0 = 0; K0 < 8; ++K0) {
        bf16x8 af = *(const bf16x8*)&xs[wave * 16 + nl][K0 * 32 + q * 8];
        bf16x8 b0 = *(const bf16x8*)&Bp2[((size_t)(K0 * 32 + nl) * 4 + q) * 8];
        bf16x8 b1v = *(const bf16x8*)&Bp2[((size_t)(K0 * 32 + 16 + nl) * 4 + q) * 8];
        acc0 = __builtin_amdgcn_mfma_f32_16x16x32_bf16(af, b0, acc0, 0, 0, 0);
        acc1 = __builtin_amdgcn_mfma_f32_16x16x32_bf16(af, b1v, acc1, 0, 0, 0);
    }
    float a_s0 = a_src2[nl], a_s1 = a_src2[16 + nl];
    float a_d0 = a_dst2[nl], a_d1 = a_dst2[16 + nl];
#pragma unroll
    for (int r = 0; r < 4; ++r) {
        int gr = row0 + wave * 16 + q * 4 + r;
        if (gr < N_NODES) {
            h2[(size_t)gr * OUT_DIM + nl] = acc0[r];
            h2[(size_t)gr * OUT_DIM + 16 + nl] = acc1[r];
            float ps = acc0[r] * a_s0 + acc1[r] * a_s1;
            float pd = acc0[r] * a_d0 + acc1[r] * a_d1;
#pragma unroll
            for (int m = 8; m >= 1; m >>= 1) {
                ps += __shfl_xor(ps, m, 16);
                pd += __shfl_xor(pd, m, 16);
            }
            if (nl == 0) { as2[gr] = ps; ad2[gr] = pd; }
        }
    }
}

// ================================================================ agg2: 1 wave/dst, 8 edges x 8 lanes x float4
__global__ __launch_bounds__(256) void agg2_kernel(const int* __restrict__ csr_src,
                                                   const int* __restrict__ row_start,
                                                   const float* __restrict__ h2,
                                                   const float* __restrict__ as2,
                                                   const float* __restrict__ ad2,
                                                   const float* __restrict__ b2,
                                                   float* __restrict__ out) {
    int n = (blockIdx.x * 256 + threadIdx.x) >> 6;
    if (n >= N_NODES) return;
    int lane = threadIdx.x & 63;
    int g  = lane >> 3;          // edge slot 0..7
    int c4 = lane & 7;           // float4 chunk: cols [c4*4, c4*4+4)
    int beg = row_start[n], end = row_start[n + 1];
    float ad = ad2[n];
    float4 acc = make_float4(0.f, 0.f, 0.f, 0.f);
    float sumw = 0.f;
    for (int i = beg; i < end; i += 8) {
        int idx = i + g;
        bool valid = idx < end;
        int ic = valid ? idx : beg;
        int s = csr_src[ic];
        float l = as2[s] + ad;
        l = l > 0.f ? l : NEG_SLOPE * l;
        float w = valid ? __expf(l) : 0.f;
        sumw += w;
        float4 hv = *(const float4*)&h2[(size_t)s * OUT_DIM + c4 * 4];
        acc.x += w * hv.x; acc.y += w * hv.y; acc.z += w * hv.z; acc.w += w * hv.w;
    }
#pragma unroll
    for (int m = 8; m <= 32; m <<= 1) {
        sumw  += __shfl_xor(sumw, m, 64);
        acc.x += __shfl_xor(acc.x, m, 64);
        acc.y += __shfl_xor(acc.y, m, 64);
        acc.z += __shfl_xor(acc.z, m, 64);
        acc.w += __shfl_xor(acc.w, m, 64);
    }
    if (g == 0) {
        float inv = 1.f / (sumw + 1e-16f);
        const float4 bv = *(const float4*)&b2[c4 * 4];
        *(float4*)&out[(size_t)n * OUT_DIM + c4 * 4] =
            make_float4(acc.x * inv + bv.x, acc.y * inv + bv.y,
                        acc.z * inv + bv.z, acc.w * inv + bv.w);
    }
}

extern "C" void kernel_launch(void* const* d_in, const int* in_sizes, int n_in,
                              void* d_out, int out_size, void* d_ws, size_t ws_size,
                              hipStream_t stream) {
    const float* x      = (const float*)d_in[0];
    const int*   ei     = (const int*)d_in[1];
    const float* W1     = (const float*)d_in[2];
    const float* a_src1 = (const float*)d_in[3];
    const float* a_dst1 = (const float*)d_in[4];
    const float* b1     = (const float*)d_in[5];
    const float* W2     = (const float*)d_in[6];
    const float* a_src2 = (const float*)d_in[7];
    const float* a_dst2 = (const float*)d_in[8];
    const float* b2     = (const float*)d_in[9];
    float* out = (float*)d_out;

    // workspace layout
    unsigned short* h1b = (unsigned short*)d_ws;        // 12.8M bf16
    unsigned short* hpb = h1b + 12800000;               // 12.8M bf16
    unsigned short* Bp1 = hpb + 12800000;               // 32768 bf16
    unsigned short* Bp2 = Bp1 + 32768;                  // 8192 bf16
    float* h2     = (float*)(Bp2 + 8192);               // 1.6M fp32
    float* as1    = h2 + 1600000;                       // 200k
    float* ad1    = as1 + 200000;                       // 200k
    float* as2    = ad1 + 200000;                       // 50k
    float* ad2    = as2 + 50000;                        // 50k
    int* csr_src  = (int*)(ad2 + 50000);                // 850k
    int* row_start= csr_src + E_TOT;                    // 50001
    int* deg      = row_start + (N_NODES + 1);          // 50k  \ adjacent:
    int* cursor   = deg + N_NODES;                      // 50k  / single memset
    int* incl     = cursor + N_NODES;                   // 50k
    int* blocksum = incl + N_NODES;                     // 256

    hipMemsetAsync(deg, 0, (size_t)(2 * N_NODES) * 4, stream);  // deg + cursor

    const int EB = (E_TOT + 255) / 256;
    setup_kernel<<<160, 256, 0, stream>>>(W1, W2, Bp1, Bp2);
    deg_kernel<<<EB, 256, 0, stream>>>(ei, deg);
    scanA_kernel<<<SCAN_NBLK, 256, 0, stream>>>(deg, incl, blocksum);
    scanC_kernel<<<SCAN_NBLK, 256, 0, stream>>>(deg, incl, blocksum, row_start);
    scatter_kernel<<<EB, 256, 0, stream>>>(ei, row_start, cursor, csr_src);

    // layer 1
    gemm1_kernel<<<N_NODES / 16, 256, 0, stream>>>(x, Bp1, a_src1, a_dst1, h1b, as1, ad1);
    agg1_kernel<<<(N_NODES * 64 + 255) / 256, 256, 0, stream>>>(csr_src, row_start, h1b, as1, ad1, b1, hpb);

    // layer 2
    gemm2_kernel<<<(N_NODES + 63) / 64, 256, 0, stream>>>(hpb, Bp2, a_src2, a_dst2, h2, as2, ad2);
    agg2_kernel<<<(N_NODES * 64 + 255) / 256, 256, 0, stream>>>(csr_src, row_start, h2, as2, ad2, b2, out);
}

// Round 6
// 302.882 us; speedup vs baseline: 11.9662x; 1.0298x over previous
//
#include <hip/hip_runtime.h>
#include <hip/hip_bf16.h>

#define N_NODES 50000
#define N_EDGES 800000
#define E_TOT   850000   // edges + self loops
#define IN_DIM  128
#define C1      256      // HEADS*HID
#define HEADS   4
#define HID     64
#define OUT_DIM 32
#define NEG_SLOPE 0.2f
#define SCAN_NBLK 196    // ceil(50000/256)

typedef __attribute__((ext_vector_type(8))) short bf16x8;
typedef __attribute__((ext_vector_type(8))) unsigned short u16x8;
typedef __attribute__((ext_vector_type(4))) float f32x4;

__device__ __forceinline__ void edge_sd(const int* __restrict__ ei, int e, int& s, int& d) {
    if (e < N_EDGES) { s = ei[e]; d = ei[N_EDGES + e]; }
    else             { s = d = e - N_EDGES; }
}

__device__ __forceinline__ unsigned short f2bf(float f) {
    unsigned u = __float_as_uint(f);
    u += 0x7fffu + ((u >> 16) & 1u);   // RNE
    return (unsigned short)(u >> 16);
}
__device__ __forceinline__ float bf2f(unsigned short u) {
    return __uint_as_float(((unsigned)u) << 16);
}
__device__ __forceinline__ float4 bf4_to_f4(ushort4 v) {
    return make_float4(bf2f(v.x), bf2f(v.y), bf2f(v.z), bf2f(v.w));
}

// ================================================================ setup: zero deg+cursor, pack W1/W2 to bf16 B-fragment order
__global__ __launch_bounds__(256) void setup_kernel(const float* __restrict__ W1,
                                                    const float* __restrict__ W2,
                                                    unsigned short* __restrict__ Bp1,
                                                    unsigned short* __restrict__ Bp2,
                                                    int* __restrict__ degcur) {
    int tid = blockIdx.x * 256 + threadIdx.x;
    if (tid < 2 * N_NODES) degcur[tid] = 0;
    if (tid < IN_DIM * C1) {
        int j = tid & 7, q = (tid >> 3) & 3, n = (tid >> 5) & 255, K0 = tid >> 13;
        int k = K0 * 32 + q * 8 + j;
        Bp1[tid] = f2bf(W1[k * C1 + n]);
        if (tid < C1 * OUT_DIM) {
            int j2 = tid & 7, q2 = (tid >> 3) & 3, n2 = (tid >> 5) & 31, K02 = tid >> 10;
            int k2 = K02 * 32 + q2 * 8 + j2;
            Bp2[tid] = f2bf(W2[k2 * OUT_DIM + n2]);
        }
    }
}

// ================================================================ CSR build
__global__ __launch_bounds__(256) void deg_kernel(const int* __restrict__ ei,
                                                  int* __restrict__ deg) {
    int e = blockIdx.x * 256 + threadIdx.x;
    if (e >= E_TOT) return;
    int s, d; edge_sd(ei, e, s, d);
    atomicAdd(&deg[d], 1);
}

__global__ __launch_bounds__(256) void scanA_kernel(const int* __restrict__ deg,
                                                    int* __restrict__ incl,
                                                    int* __restrict__ blocksum) {
    __shared__ int sm[256];
    int t = threadIdx.x, idx = blockIdx.x * 256 + t;
    int v = (idx < N_NODES) ? deg[idx] : 0;
    sm[t] = v; __syncthreads();
#pragma unroll
    for (int off = 1; off < 256; off <<= 1) {
        int u = (t >= off) ? sm[t - off] : 0;
        __syncthreads();
        sm[t] += u;
        __syncthreads();
    }
    if (idx < N_NODES) incl[idx] = sm[t];
    if (t == 255) blocksum[blockIdx.x] = sm[t];
}

__global__ __launch_bounds__(256) void scanC_kernel(const int* __restrict__ deg,
                                                    const int* __restrict__ incl,
                                                    const int* __restrict__ blocksum,
                                                    int* __restrict__ row_start) {
    __shared__ int wsum[4];
    int t = threadIdx.x;
    int v = (t < (int)blockIdx.x) ? blocksum[t] : 0;   // blockIdx.x <= 195
#pragma unroll
    for (int m = 32; m >= 1; m >>= 1) v += __shfl_xor(v, m, 64);
    if ((t & 63) == 0) wsum[t >> 6] = v;
    __syncthreads();
    int off = wsum[0] + wsum[1] + wsum[2] + wsum[3];
    int idx = blockIdx.x * 256 + t;
    if (idx >= N_NODES) return;
    row_start[idx] = off + incl[idx] - deg[idx];
    if (idx == N_NODES - 1) row_start[N_NODES] = off + incl[idx];  // == E_TOT
}

__global__ __launch_bounds__(256) void scatter_kernel(const int* __restrict__ ei,
                                                      const int* __restrict__ row_start,
                                                      int* __restrict__ cursor,
                                                      int* __restrict__ csr_src) {
    int e = blockIdx.x * 256 + threadIdx.x;
    if (e >= E_TOT) return;
    int s, d; edge_sd(ei, e, s, d);
    int pos = atomicAdd(&cursor[d], 1);
    csr_src[row_start[d] + pos] = s;
}

// ================================================================ GEMM1 (MFMA bf16) + fused alpha1
__global__ __launch_bounds__(256) void gemm1_kernel(const float* __restrict__ x,
                                                    const unsigned short* __restrict__ Bp,
                                                    const float* __restrict__ a_src1,
                                                    const float* __restrict__ a_dst1,
                                                    unsigned short* __restrict__ h1b,
                                                    float* __restrict__ as1,
                                                    float* __restrict__ ad1) {
    __shared__ unsigned short xs[16][136];  // +8 pad -> 2-way LDS aliasing (free)
    const int t = threadIdx.x;
    const int row0 = blockIdx.x * 16;
    {
        int r = t >> 4, k0 = (t & 15) * 8;
        const float* xp = &x[(size_t)(row0 + r) * IN_DIM + k0];
        float4 v0 = *(const float4*)xp;
        float4 v1 = *(const float4*)(xp + 4);
        ushort4 o0, o1;
        o0.x = f2bf(v0.x); o0.y = f2bf(v0.y); o0.z = f2bf(v0.z); o0.w = f2bf(v0.w);
        o1.x = f2bf(v1.x); o1.y = f2bf(v1.y); o1.z = f2bf(v1.z); o1.w = f2bf(v1.w);
        *(ushort4*)&xs[r][k0] = o0;
        *(ushort4*)&xs[r][k0 + 4] = o1;
    }
    __syncthreads();
    const int wave = t >> 6;         // head index
    const int lane = t & 63;
    const int nl = lane & 15, q = lane >> 4;
    f32x4 acc[4];
    f32x4 z = {0.f, 0.f, 0.f, 0.f};
    acc[0] = z; acc[1] = z; acc[2] = z; acc[3] = z;
#pragma unroll
    for (int K0 = 0; K0 < 4; ++K0) {
        bf16x8 af = *(const bf16x8*)&xs[nl][K0 * 32 + q * 8];
#pragma unroll
        for (int sub = 0; sub < 4; ++sub) {
            int n = wave * 64 + sub * 16 + nl;
            bf16x8 bfv = *(const bf16x8*)&Bp[((size_t)(K0 * 256 + n) * 4 + q) * 8];
            acc[sub] = __builtin_amdgcn_mfma_f32_16x16x32_bf16(af, bfv, acc[sub], 0, 0, 0);
        }
    }
    float asv[4], adv[4];
#pragma unroll
    for (int sub = 0; sub < 4; ++sub) {
        asv[sub] = a_src1[wave * 64 + sub * 16 + nl];
        adv[sub] = a_dst1[wave * 64 + sub * 16 + nl];
    }
#pragma unroll
    for (int r = 0; r < 4; ++r) {
        int gr = row0 + q * 4 + r;   // C/D: row = quad*4 + reg, col = lane&15
        float ps = 0.f, pd = 0.f;
#pragma unroll
        for (int sub = 0; sub < 4; ++sub) {
            float v = acc[sub][r];
            h1b[(size_t)gr * C1 + wave * 64 + sub * 16 + nl] = f2bf(v);
            ps += v * asv[sub];
            pd += v * adv[sub];
        }
#pragma unroll
        for (int m = 8; m >= 1; m >>= 1) {
            ps += __shfl_xor(ps, m, 16);
            pd += __shfl_xor(pd, m, 16);
        }
        if (nl == 0) {
            as1[gr * 4 + wave] = ps;
            ad1[gr * 4 + wave] = pd;
        }
    }
}

// ================================================================ agg1: 1 wave/dst, 64 lanes x ushort4 per edge, unroll 8
__global__ __launch_bounds__(256) void agg1_kernel(const int* __restrict__ csr_src,
                                                   const int* __restrict__ row_start,
                                                   const unsigned short* __restrict__ h1b,
                                                   const float* __restrict__ as1,
                                                   const float* __restrict__ ad1,
                                                   const float* __restrict__ b1,
                                                   unsigned short* __restrict__ hpb) {
    int n = (blockIdx.x * 256 + threadIdx.x) >> 6;
    if (n >= N_NODES) return;
    int lane = threadIdx.x & 63;
    int h = lane >> 4;
    int beg = row_start[n], end = row_start[n + 1];
    float ad = ad1[n * 4 + h];
    float4 acc = make_float4(0.f, 0.f, 0.f, 0.f);
    float sumw = 0.f;
    int i = beg;
    for (; i + 8 <= end; i += 8) {              // unmasked main loop, 8-way MLP
        int s[8];
#pragma unroll
        for (int u = 0; u < 8; ++u) s[u] = csr_src[i + u];
        ushort4 rv[8];
#pragma unroll
        for (int u = 0; u < 8; ++u) rv[u] = *(const ushort4*)&h1b[(size_t)s[u] * C1 + lane * 4];
        float a[8];
#pragma unroll
        for (int u = 0; u < 8; ++u) a[u] = as1[s[u] * 4 + h];
#pragma unroll
        for (int u = 0; u < 8; ++u) {
            float l = a[u] + ad;
            l = l > 0.f ? l : NEG_SLOPE * l;
            float w = __expf(l);
            sumw += w;
            float4 f = bf4_to_f4(rv[u]);
            acc.x += w * f.x; acc.y += w * f.y; acc.z += w * f.z; acc.w += w * f.w;
        }
    }
    if (i < end) {                               // masked tail, still 8-way MLP
        int s[8]; bool va[8];
#pragma unroll
        for (int u = 0; u < 8; ++u) {
            va[u] = (i + u) < end;
            s[u] = csr_src[va[u] ? i + u : beg];
        }
        ushort4 rv[8];
#pragma unroll
        for (int u = 0; u < 8; ++u) rv[u] = *(const ushort4*)&h1b[(size_t)s[u] * C1 + lane * 4];
        float a[8];
#pragma unroll
        for (int u = 0; u < 8; ++u) a[u] = as1[s[u] * 4 + h];
#pragma unroll
        for (int u = 0; u < 8; ++u) {
            float l = a[u] + ad;
            l = l > 0.f ? l : NEG_SLOPE * l;
            float w = va[u] ? __expf(l) : 0.f;
            sumw += w;
            float4 f = bf4_to_f4(rv[u]);
            acc.x += w * f.x; acc.y += w * f.y; acc.z += w * f.z; acc.w += w * f.w;
        }
    }
    float inv = 1.f / (sumw + 1e-16f);
    const float4 bv = *(const float4*)&b1[lane * 4];
    float v0 = acc.x * inv + bv.x;
    float v1 = acc.y * inv + bv.y;
    float v2 = acc.z * inv + bv.z;
    float v3 = acc.w * inv + bv.w;
    v0 = v0 > 0.f ? v0 : __expf(v0) - 1.f;
    v1 = v1 > 0.f ? v1 : __expf(v1) - 1.f;
    v2 = v2 > 0.f ? v2 : __expf(v2) - 1.f;
    v3 = v3 > 0.f ? v3 : __expf(v3) - 1.f;
    ushort4 o;
    o.x = f2bf(v0); o.y = f2bf(v1); o.z = f2bf(v2); o.w = f2bf(v3);
    *(ushort4*)&hpb[(size_t)n * C1 + lane * 4] = o;
}

// ================================================================ GEMM2 (MFMA bf16) + fused alpha2; h2 stored bf16
__global__ __launch_bounds__(256) void gemm2_kernel(const unsigned short* __restrict__ hpb,
                                                    const unsigned short* __restrict__ Bp2,
                                                    const float* __restrict__ a_src2,
                                                    const float* __restrict__ a_dst2,
                                                    unsigned short* __restrict__ h2b,
                                                    float* __restrict__ as2,
                                                    float* __restrict__ ad2) {
    __shared__ unsigned short xs[64][264];  // stride 264 shorts -> 2-way bank aliasing (free)
    const int t = threadIdx.x;
    const int row0 = blockIdx.x * 64;
    for (int idx = t; idx < 2048; idx += 256) {  // 64 rows x 32 chunks of 8
        int r = idx >> 5, ch = (idx & 31) * 8;
        int gr = row0 + r;
        u16x8 v = {0, 0, 0, 0, 0, 0, 0, 0};
        if (gr < N_NODES) v = *(const u16x8*)&hpb[(size_t)gr * C1 + ch];
        *(u16x8*)&xs[r][ch] = v;
    }
    __syncthreads();
    const int wave = t >> 6, lane = t & 63;
    const int nl = lane & 15, q = lane >> 4;
    f32x4 acc0 = {0.f, 0.f, 0.f, 0.f}, acc1 = {0.f, 0.f, 0.f, 0.f};
#pragma unroll
    for (int K0 = 0; K0 < 8; ++K0) {
        bf16x8 af = *(const bf16x8*)&xs[wave * 16 + nl][K0 * 32 + q * 8];
        bf16x8 b0 = *(const bf16x8*)&Bp2[((size_t)(K0 * 32 + nl) * 4 + q) * 8];
        bf16x8 b1v = *(const bf16x8*)&Bp2[((size_t)(K0 * 32 + 16 + nl) * 4 + q) * 8];
        acc0 = __builtin_amdgcn_mfma_f32_16x16x32_bf16(af, b0, acc0, 0, 0, 0);
        acc1 = __builtin_amdgcn_mfma_f32_16x16x32_bf16(af, b1v, acc1, 0, 0, 0);
    }
    float a_s0 = a_src2[nl], a_s1 = a_src2[16 + nl];
    float a_d0 = a_dst2[nl], a_d1 = a_dst2[16 + nl];
#pragma unroll
    for (int r = 0; r < 4; ++r) {
        int gr = row0 + wave * 16 + q * 4 + r;
        if (gr < N_NODES) {
            h2b[(size_t)gr * OUT_DIM + nl] = f2bf(acc0[r]);
            h2b[(size_t)gr * OUT_DIM + 16 + nl] = f2bf(acc1[r]);
            float ps = acc0[r] * a_s0 + acc1[r] * a_s1;
            float pd = acc0[r] * a_d0 + acc1[r] * a_d1;
#pragma unroll
            for (int m = 8; m >= 1; m >>= 1) {
                ps += __shfl_xor(ps, m, 16);
                pd += __shfl_xor(pd, m, 16);
            }
            if (nl == 0) { as2[gr] = ps; ad2[gr] = pd; }
        }
    }
}

// ================================================================ agg2: 1 wave/dst, 8 edges x 8 lanes x ushort4 (bf16 h2)
__global__ __launch_bounds__(256) void agg2_kernel(const int* __restrict__ csr_src,
                                                   const int* __restrict__ row_start,
                                                   const unsigned short* __restrict__ h2b,
                                                   const float* __restrict__ as2,
                                                   const float* __restrict__ ad2,
                                                   const float* __restrict__ b2,
                                                   float* __restrict__ out) {
    int n = (blockIdx.x * 256 + threadIdx.x) >> 6;
    if (n >= N_NODES) return;
    int lane = threadIdx.x & 63;
    int g  = lane >> 3;          // edge slot 0..7
    int c4 = lane & 7;           // ushort4 chunk: cols [c4*4, c4*4+4)
    int beg = row_start[n], end = row_start[n + 1];
    float ad = ad2[n];
    float4 acc = make_float4(0.f, 0.f, 0.f, 0.f);
    float sumw = 0.f;
    for (int i = beg; i < end; i += 8) {
        int idx = i + g;
        bool valid = idx < end;
        int ic = valid ? idx : beg;
        int s = csr_src[ic];
        float l = as2[s] + ad;
        l = l > 0.f ? l : NEG_SLOPE * l;
        float w = valid ? __expf(l) : 0.f;
        sumw += w;
        float4 hv = bf4_to_f4(*(const ushort4*)&h2b[(size_t)s * OUT_DIM + c4 * 4]);
        acc.x += w * hv.x; acc.y += w * hv.y; acc.z += w * hv.z; acc.w += w * hv.w;
    }
#pragma unroll
    for (int m = 8; m <= 32; m <<= 1) {
        sumw  += __shfl_xor(sumw, m, 64);
        acc.x += __shfl_xor(acc.x, m, 64);
        acc.y += __shfl_xor(acc.y, m, 64);
        acc.z += __shfl_xor(acc.z, m, 64);
        acc.w += __shfl_xor(acc.w, m, 64);
    }
    if (g == 0) {
        float inv = 1.f / (sumw + 1e-16f);
        const float4 bv = *(const float4*)&b2[c4 * 4];
        *(float4*)&out[(size_t)n * OUT_DIM + c4 * 4] =
            make_float4(acc.x * inv + bv.x, acc.y * inv + bv.y,
                        acc.z * inv + bv.z, acc.w * inv + bv.w);
    }
}

extern "C" void kernel_launch(void* const* d_in, const int* in_sizes, int n_in,
                              void* d_out, int out_size, void* d_ws, size_t ws_size,
                              hipStream_t stream) {
    const float* x      = (const float*)d_in[0];
    const int*   ei     = (const int*)d_in[1];
    const float* W1     = (const float*)d_in[2];
    const float* a_src1 = (const float*)d_in[3];
    const float* a_dst1 = (const float*)d_in[4];
    const float* b1     = (const float*)d_in[5];
    const float* W2     = (const float*)d_in[6];
    const float* a_src2 = (const float*)d_in[7];
    const float* a_dst2 = (const float*)d_in[8];
    const float* b2     = (const float*)d_in[9];
    float* out = (float*)d_out;

    // workspace layout
    unsigned short* h1b = (unsigned short*)d_ws;        // 12.8M bf16
    unsigned short* hpb = h1b + 12800000;               // 12.8M bf16
    unsigned short* h2b = hpb + 12800000;               // 1.6M bf16
    unsigned short* Bp1 = h2b + 1600000;                // 32768 bf16
    unsigned short* Bp2 = Bp1 + 32768;                  // 8192 bf16
    float* as1    = (float*)(Bp2 + 8192);               // 200k
    float* ad1    = as1 + 200000;                       // 200k
    float* as2    = ad1 + 200000;                       // 50k
    float* ad2    = as2 + 50000;                        // 50k
    int* csr_src  = (int*)(ad2 + 50000);                // 850k
    int* row_start= csr_src + E_TOT;                    // 50001
    int* deg      = row_start + (N_NODES + 1);          // 50k  \ adjacent:
    int* cursor   = deg + N_NODES;                      // 50k  / zeroed together
    int* incl     = cursor + N_NODES;                   // 50k
    int* blocksum = incl + N_NODES;                     // 256

    const int EB = (E_TOT + 255) / 256;
    setup_kernel<<<391, 256, 0, stream>>>(W1, W2, Bp1, Bp2, deg);  // zeros deg+cursor
    deg_kernel<<<EB, 256, 0, stream>>>(ei, deg);
    scanA_kernel<<<SCAN_NBLK, 256, 0, stream>>>(deg, incl, blocksum);
    scanC_kernel<<<SCAN_NBLK, 256, 0, stream>>>(deg, incl, blocksum, row_start);
    scatter_kernel<<<EB, 256, 0, stream>>>(ei, row_start, cursor, csr_src);

    // layer 1
    gemm1_kernel<<<N_NODES / 16, 256, 0, stream>>>(x, Bp1, a_src1, a_dst1, h1b, as1, ad1);
    agg1_kernel<<<(N_NODES * 64 + 255) / 256, 256, 0, stream>>>(csr_src, row_start, h1b, as1, ad1, b1, hpb);

    // layer 2
    gemm2_kernel<<<(N_NODES + 63) / 64, 256, 0, stream>>>(hpb, Bp2, a_src2, a_dst2, h2b, as2, ad2);
    agg2_kernel<<<(N_NODES * 64 + 255) / 256, 256, 0, stream>>>(csr_src, row_start, h2b, as2, ad2, b2, out);
}

// Round 7
// 272.851 us; speedup vs baseline: 13.2832x; 1.1101x over previous
//
#include <hip/hip_runtime.h>
#include <hip/hip_bf16.h>

#define N_NODES 50000
#define N_EDGES 800000
#define E_TOT   850000   // edges + self loops
#define IN_DIM  128
#define C1      256      // HEADS*HID
#define HEADS   4
#define HID     64
#define OUT_DIM 32
#define NEG_SLOPE 0.2f
#define SCAN_NBLK 196    // ceil(50000/256)

typedef __attribute__((ext_vector_type(8))) short bf16x8;
typedef __attribute__((ext_vector_type(8))) unsigned short u16x8;
typedef __attribute__((ext_vector_type(4))) float f32x4;

__device__ __forceinline__ void edge_sd(const int* __restrict__ ei, int e, int& s, int& d) {
    if (e < N_EDGES) { s = ei[e]; d = ei[N_EDGES + e]; }
    else             { s = d = e - N_EDGES; }
}

__device__ __forceinline__ unsigned short f2bf(float f) {
    unsigned u = __float_as_uint(f);
    u += 0x7fffu + ((u >> 16) & 1u);   // RNE
    return (unsigned short)(u >> 16);
}
__device__ __forceinline__ float bf2f(unsigned short u) {
    return __uint_as_float(((unsigned)u) << 16);
}
__device__ __forceinline__ float4 bf4_to_f4(ushort4 v) {
    return make_float4(bf2f(v.x), bf2f(v.y), bf2f(v.z), bf2f(v.w));
}

// ================================================================ setup: zero deg, pack W1/W2 to bf16 B-fragment order
__global__ __launch_bounds__(256) void setup_kernel(const float* __restrict__ W1,
                                                    const float* __restrict__ W2,
                                                    unsigned short* __restrict__ Bp1,
                                                    unsigned short* __restrict__ Bp2,
                                                    int* __restrict__ deg) {
    int tid = blockIdx.x * 256 + threadIdx.x;
    if (tid < N_NODES) deg[tid] = 0;
    if (tid < IN_DIM * C1) {
        int j = tid & 7, q = (tid >> 3) & 3, n = (tid >> 5) & 255, K0 = tid >> 13;
        int k = K0 * 32 + q * 8 + j;
        Bp1[tid] = f2bf(W1[k * C1 + n]);
        if (tid < C1 * OUT_DIM) {
            int j2 = tid & 7, q2 = (tid >> 3) & 3, n2 = (tid >> 5) & 31, K02 = tid >> 10;
            int k2 = K02 * 32 + q2 * 8 + j2;
            Bp2[tid] = f2bf(W2[k2 * OUT_DIM + n2]);
        }
    }
}

// ================================================================ CSR build
// deg + per-edge slot (removes atomic from scatter)
__global__ __launch_bounds__(256) void deg_kernel(const int* __restrict__ ei,
                                                  int* __restrict__ deg,
                                                  int* __restrict__ pos) {
    int e = blockIdx.x * 256 + threadIdx.x;
    if (e >= E_TOT) return;
    int s, d; edge_sd(ei, e, s, d);
    pos[e] = atomicAdd(&deg[d], 1);
}

__global__ __launch_bounds__(256) void scanA_kernel(const int* __restrict__ deg,
                                                    int* __restrict__ incl,
                                                    int* __restrict__ blocksum) {
    __shared__ int sm[256];
    int t = threadIdx.x, idx = blockIdx.x * 256 + t;
    int v = (idx < N_NODES) ? deg[idx] : 0;
    sm[t] = v; __syncthreads();
#pragma unroll
    for (int off = 1; off < 256; off <<= 1) {
        int u = (t >= off) ? sm[t - off] : 0;
        __syncthreads();
        sm[t] += u;
        __syncthreads();
    }
    if (idx < N_NODES) incl[idx] = sm[t];
    if (t == 255) blocksum[blockIdx.x] = sm[t];
}

__global__ __launch_bounds__(256) void scanC_kernel(const int* __restrict__ deg,
                                                    const int* __restrict__ incl,
                                                    const int* __restrict__ blocksum,
                                                    int* __restrict__ row_start) {
    __shared__ int wsum[4];
    int t = threadIdx.x;
    int v = (t < (int)blockIdx.x) ? blocksum[t] : 0;   // blockIdx.x <= 195
#pragma unroll
    for (int m = 32; m >= 1; m >>= 1) v += __shfl_xor(v, m, 64);
    if ((t & 63) == 0) wsum[t >> 6] = v;
    __syncthreads();
    int off = wsum[0] + wsum[1] + wsum[2] + wsum[3];
    int idx = blockIdx.x * 256 + t;
    if (idx >= N_NODES) return;
    row_start[idx] = off + incl[idx] - deg[idx];
    if (idx == N_NODES - 1) row_start[N_NODES] = off + incl[idx];  // == E_TOT
}

// scatter + edge-weight compute (runs AFTER gemm1 so as1/ad1 are ready)
__global__ __launch_bounds__(256) void scatter_w_kernel(const int* __restrict__ ei,
                                                        const int* __restrict__ row_start,
                                                        const int* __restrict__ pos,
                                                        const float* __restrict__ as1,
                                                        const float* __restrict__ ad1,
                                                        int* __restrict__ csr_src,
                                                        float* __restrict__ wc) {
    int e = blockIdx.x * 256 + threadIdx.x;
    if (e >= E_TOT) return;
    int s, d; edge_sd(ei, e, s, d);
    int p = row_start[d] + pos[e];
    csr_src[p] = s;
    float4 av = *(const float4*)&as1[s * 4];
    float4 bv = *(const float4*)&ad1[d * 4];
    float l0 = av.x + bv.x, l1 = av.y + bv.y, l2 = av.z + bv.z, l3 = av.w + bv.w;
    l0 = l0 > 0.f ? l0 : NEG_SLOPE * l0;
    l1 = l1 > 0.f ? l1 : NEG_SLOPE * l1;
    l2 = l2 > 0.f ? l2 : NEG_SLOPE * l2;
    l3 = l3 > 0.f ? l3 : NEG_SLOPE * l3;
    *(float4*)&wc[(size_t)p * 4] =
        make_float4(__expf(l0), __expf(l1), __expf(l2), __expf(l3));
}

// ================================================================ GEMM1 (MFMA bf16) + fused alpha1
__global__ __launch_bounds__(256) void gemm1_kernel(const float* __restrict__ x,
                                                    const unsigned short* __restrict__ Bp,
                                                    const float* __restrict__ a_src1,
                                                    const float* __restrict__ a_dst1,
                                                    unsigned short* __restrict__ h1b,
                                                    float* __restrict__ as1,
                                                    float* __restrict__ ad1) {
    __shared__ unsigned short xs[16][136];  // +8 pad -> 2-way LDS aliasing (free)
    const int t = threadIdx.x;
    const int row0 = blockIdx.x * 16;
    {
        int r = t >> 4, k0 = (t & 15) * 8;
        const float* xp = &x[(size_t)(row0 + r) * IN_DIM + k0];
        float4 v0 = *(const float4*)xp;
        float4 v1 = *(const float4*)(xp + 4);
        ushort4 o0, o1;
        o0.x = f2bf(v0.x); o0.y = f2bf(v0.y); o0.z = f2bf(v0.z); o0.w = f2bf(v0.w);
        o1.x = f2bf(v1.x); o1.y = f2bf(v1.y); o1.z = f2bf(v1.z); o1.w = f2bf(v1.w);
        *(ushort4*)&xs[r][k0] = o0;
        *(ushort4*)&xs[r][k0 + 4] = o1;
    }
    __syncthreads();
    const int wave = t >> 6;         // head index
    const int lane = t & 63;
    const int nl = lane & 15, q = lane >> 4;
    f32x4 acc[4];
    f32x4 z = {0.f, 0.f, 0.f, 0.f};
    acc[0] = z; acc[1] = z; acc[2] = z; acc[3] = z;
#pragma unroll
    for (int K0 = 0; K0 < 4; ++K0) {
        bf16x8 af = *(const bf16x8*)&xs[nl][K0 * 32 + q * 8];
#pragma unroll
        for (int sub = 0; sub < 4; ++sub) {
            int n = wave * 64 + sub * 16 + nl;
            bf16x8 bfv = *(const bf16x8*)&Bp[((size_t)(K0 * 256 + n) * 4 + q) * 8];
            acc[sub] = __builtin_amdgcn_mfma_f32_16x16x32_bf16(af, bfv, acc[sub], 0, 0, 0);
        }
    }
    float asv[4], adv[4];
#pragma unroll
    for (int sub = 0; sub < 4; ++sub) {
        asv[sub] = a_src1[wave * 64 + sub * 16 + nl];
        adv[sub] = a_dst1[wave * 64 + sub * 16 + nl];
    }
#pragma unroll
    for (int r = 0; r < 4; ++r) {
        int gr = row0 + q * 4 + r;   // C/D: row = quad*4 + reg, col = lane&15
        float ps = 0.f, pd = 0.f;
#pragma unroll
        for (int sub = 0; sub < 4; ++sub) {
            float v = acc[sub][r];
            h1b[(size_t)gr * C1 + wave * 64 + sub * 16 + nl] = f2bf(v);
            ps += v * asv[sub];
            pd += v * adv[sub];
        }
#pragma unroll
        for (int m = 8; m >= 1; m >>= 1) {
            ps += __shfl_xor(ps, m, 16);
            pd += __shfl_xor(pd, m, 16);
        }
        if (nl == 0) {
            as1[gr * 4 + wave] = ps;
            ad1[gr * 4 + wave] = pd;
        }
    }
}

// ================================================================ agg1: 1 wave/dst, precomputed CSR weights, scalar-uniform addressing
__global__ __launch_bounds__(256) void agg1_kernel(const int* __restrict__ csr_src,
                                                   const int* __restrict__ row_start,
                                                   const unsigned short* __restrict__ h1b,
                                                   const float* __restrict__ wc,
                                                   const float* __restrict__ b1,
                                                   unsigned short* __restrict__ hpb) {
    int n = (blockIdx.x * 256 + threadIdx.x) >> 6;
    if (n >= N_NODES) return;
    int lane = threadIdx.x & 63;
    int h = lane >> 4;
    int beg = __builtin_amdgcn_readfirstlane(row_start[n]);
    int end = __builtin_amdgcn_readfirstlane(row_start[n + 1]);
    float4 acc = make_float4(0.f, 0.f, 0.f, 0.f);
    float sumw = 0.f;
    int i = beg;
    for (; i + 8 <= end; i += 8) {              // unmasked main loop, 8-way MLP
        int s[8];
#pragma unroll
        for (int u = 0; u < 8; ++u) s[u] = __builtin_amdgcn_readfirstlane(csr_src[i + u]);
        float w[8];
#pragma unroll
        for (int u = 0; u < 8; ++u) w[u] = wc[(size_t)(i + u) * 4 + h];
        ushort4 rv[8];
#pragma unroll
        for (int u = 0; u < 8; ++u) rv[u] = *(const ushort4*)&h1b[(size_t)s[u] * C1 + lane * 4];
#pragma unroll
        for (int u = 0; u < 8; ++u) {
            sumw += w[u];
            float4 f = bf4_to_f4(rv[u]);
            acc.x += w[u] * f.x; acc.y += w[u] * f.y;
            acc.z += w[u] * f.z; acc.w += w[u] * f.w;
        }
    }
    if (i < end) {                               // masked tail, still 8-way MLP
        int s[8]; int ic[8]; bool va[8];
#pragma unroll
        for (int u = 0; u < 8; ++u) {
            va[u] = (i + u) < end;
            ic[u] = va[u] ? i + u : beg;         // safe slot (deg >= 1 via self-loop)
            s[u] = __builtin_amdgcn_readfirstlane(csr_src[ic[u]]);
        }
        float w[8];
#pragma unroll
        for (int u = 0; u < 8; ++u) w[u] = va[u] ? wc[(size_t)ic[u] * 4 + h] : 0.f;
        ushort4 rv[8];
#pragma unroll
        for (int u = 0; u < 8; ++u) rv[u] = *(const ushort4*)&h1b[(size_t)s[u] * C1 + lane * 4];
#pragma unroll
        for (int u = 0; u < 8; ++u) {
            sumw += w[u];
            float4 f = bf4_to_f4(rv[u]);
            acc.x += w[u] * f.x; acc.y += w[u] * f.y;
            acc.z += w[u] * f.z; acc.w += w[u] * f.w;
        }
    }
    float inv = 1.f / (sumw + 1e-16f);
    const float4 bv = *(const float4*)&b1[lane * 4];
    float v0 = acc.x * inv + bv.x;
    float v1 = acc.y * inv + bv.y;
    float v2 = acc.z * inv + bv.z;
    float v3 = acc.w * inv + bv.w;
    v0 = v0 > 0.f ? v0 : __expf(v0) - 1.f;
    v1 = v1 > 0.f ? v1 : __expf(v1) - 1.f;
    v2 = v2 > 0.f ? v2 : __expf(v2) - 1.f;
    v3 = v3 > 0.f ? v3 : __expf(v3) - 1.f;
    ushort4 o;
    o.x = f2bf(v0); o.y = f2bf(v1); o.z = f2bf(v2); o.w = f2bf(v3);
    *(ushort4*)&hpb[(size_t)n * C1 + lane * 4] = o;
}

// ================================================================ GEMM2 (MFMA bf16) + fused alpha2; h2 stored bf16
__global__ __launch_bounds__(256) void gemm2_kernel(const unsigned short* __restrict__ hpb,
                                                    const unsigned short* __restrict__ Bp2,
                                                    const float* __restrict__ a_src2,
                                                    const float* __restrict__ a_dst2,
                                                    unsigned short* __restrict__ h2b,
                                                    float* __restrict__ as2,
                                                    float* __restrict__ ad2) {
    __shared__ unsigned short xs[64][264];  // stride 264 shorts -> 2-way bank aliasing (free)
    const int t = threadIdx.x;
    const int row0 = blockIdx.x * 64;
    for (int idx = t; idx < 2048; idx += 256) {  // 64 rows x 32 chunks of 8
        int r = idx >> 5, ch = (idx & 31) * 8;
        int gr = row0 + r;
        u16x8 v = {0, 0, 0, 0, 0, 0, 0, 0};
        if (gr < N_NODES) v = *(const u16x8*)&hpb[(size_t)gr * C1 + ch];
        *(u16x8*)&xs[r][ch] = v;
    }
    __syncthreads();
    const int wave = t >> 6, lane = t & 63;
    const int nl = lane & 15, q = lane >> 4;
    f32x4 acc0 = {0.f, 0.f, 0.f, 0.f}, acc1 = {0.f, 0.f, 0.f, 0.f};
#pragma unroll
    for (int K0 = 0; K0 < 8; ++K0) {
        bf16x8 af = *(const bf16x8*)&xs[wave * 16 + nl][K0 * 32 + q * 8];
        bf16x8 b0 = *(const bf16x8*)&Bp2[((size_t)(K0 * 32 + nl) * 4 + q) * 8];
        bf16x8 b1v = *(const bf16x8*)&Bp2[((size_t)(K0 * 32 + 16 + nl) * 4 + q) * 8];
        acc0 = __builtin_amdgcn_mfma_f32_16x16x32_bf16(af, b0, acc0, 0, 0, 0);
        acc1 = __builtin_amdgcn_mfma_f32_16x16x32_bf16(af, b1v, acc1, 0, 0, 0);
    }
    float a_s0 = a_src2[nl], a_s1 = a_src2[16 + nl];
    float a_d0 = a_dst2[nl], a_d1 = a_dst2[16 + nl];
#pragma unroll
    for (int r = 0; r < 4; ++r) {
        int gr = row0 + wave * 16 + q * 4 + r;
        if (gr < N_NODES) {
            h2b[(size_t)gr * OUT_DIM + nl] = f2bf(acc0[r]);
            h2b[(size_t)gr * OUT_DIM + 16 + nl] = f2bf(acc1[r]);
            float ps = acc0[r] * a_s0 + acc1[r] * a_s1;
            float pd = acc0[r] * a_d0 + acc1[r] * a_d1;
#pragma unroll
            for (int m = 8; m >= 1; m >>= 1) {
                ps += __shfl_xor(ps, m, 16);
                pd += __shfl_xor(pd, m, 16);
            }
            if (nl == 0) { as2[gr] = ps; ad2[gr] = pd; }
        }
    }
}

// ================================================================ agg2: 1 wave/dst, 8 edges x 8 lanes x ushort4 (bf16 h2)
__global__ __launch_bounds__(256) void agg2_kernel(const int* __restrict__ csr_src,
                                                   const int* __restrict__ row_start,
                                                   const unsigned short* __restrict__ h2b,
                                                   const float* __restrict__ as2,
                                                   const float* __restrict__ ad2,
                                                   const float* __restrict__ b2,
                                                   float* __restrict__ out) {
    int n = (blockIdx.x * 256 + threadIdx.x) >> 6;
    if (n >= N_NODES) return;
    int lane = threadIdx.x & 63;
    int g  = lane >> 3;          // edge slot 0..7
    int c4 = lane & 7;           // ushort4 chunk: cols [c4*4, c4*4+4)
    int beg = __builtin_amdgcn_readfirstlane(row_start[n]);
    int end = __builtin_amdgcn_readfirstlane(row_start[n + 1]);
    float ad = ad2[n];
    float4 acc = make_float4(0.f, 0.f, 0.f, 0.f);
    float sumw = 0.f;
    for (int i = beg; i < end; i += 8) {
        int idx = i + g;
        bool valid = idx < end;
        int ic = valid ? idx : beg;
        int s = csr_src[ic];
        float l = as2[s] + ad;
        l = l > 0.f ? l : NEG_SLOPE * l;
        float w = valid ? __expf(l) : 0.f;
        sumw += w;
        float4 hv = bf4_to_f4(*(const ushort4*)&h2b[(size_t)s * OUT_DIM + c4 * 4]);
        acc.x += w * hv.x; acc.y += w * hv.y; acc.z += w * hv.z; acc.w += w * hv.w;
    }
#pragma unroll
    for (int m = 8; m <= 32; m <<= 1) {
        sumw  += __shfl_xor(sumw, m, 64);
        acc.x += __shfl_xor(acc.x, m, 64);
        acc.y += __shfl_xor(acc.y, m, 64);
        acc.z += __shfl_xor(acc.z, m, 64);
        acc.w += __shfl_xor(acc.w, m, 64);
    }
    if (g == 0) {
        float inv = 1.f / (sumw + 1e-16f);
        const float4 bv = *(const float4*)&b2[c4 * 4];
        *(float4*)&out[(size_t)n * OUT_DIM + c4 * 4] =
            make_float4(acc.x * inv + bv.x, acc.y * inv + bv.y,
                        acc.z * inv + bv.z, acc.w * inv + bv.w);
    }
}

extern "C" void kernel_launch(void* const* d_in, const int* in_sizes, int n_in,
                              void* d_out, int out_size, void* d_ws, size_t ws_size,
                              hipStream_t stream) {
    const float* x      = (const float*)d_in[0];
    const int*   ei     = (const int*)d_in[1];
    const float* W1     = (const float*)d_in[2];
    const float* a_src1 = (const float*)d_in[3];
    const float* a_dst1 = (const float*)d_in[4];
    const float* b1     = (const float*)d_in[5];
    const float* W2     = (const float*)d_in[6];
    const float* a_src2 = (const float*)d_in[7];
    const float* a_dst2 = (const float*)d_in[8];
    const float* b2     = (const float*)d_in[9];
    float* out = (float*)d_out;

    // workspace layout
    unsigned short* h1b = (unsigned short*)d_ws;        // 12.8M bf16
    unsigned short* hpb = h1b + 12800000;               // 12.8M bf16
    unsigned short* h2b = hpb + 12800000;               // 1.6M bf16
    unsigned short* Bp1 = h2b + 1600000;                // 32768 bf16
    unsigned short* Bp2 = Bp1 + 32768;                  // 8192 bf16
    float* as1    = (float*)(Bp2 + 8192);               // 200k
    float* ad1    = as1 + 200000;                       // 200k
    float* as2    = ad1 + 200000;                       // 50k
    float* ad2    = as2 + 50000;                        // 50k
    float* wc     = ad2 + 50000;                        // 3.4M (CSR-ordered edge weights, 4 heads)
    int* csr_src  = (int*)(wc + (size_t)E_TOT * 4);     // 850k
    int* row_start= csr_src + E_TOT;                    // 50001
    int* deg      = row_start + (N_NODES + 1);          // 50k
    int* pos      = deg + N_NODES;                      // 850k
    int* incl     = pos + E_TOT;                        // 50k
    int* blocksum = incl + N_NODES;                     // 256

    const int EB = (E_TOT + 255) / 256;
    setup_kernel<<<SCAN_NBLK, 256, 0, stream>>>(W1, W2, Bp1, Bp2, deg);  // zeros deg
    deg_kernel<<<EB, 256, 0, stream>>>(ei, deg, pos);
    scanA_kernel<<<SCAN_NBLK, 256, 0, stream>>>(deg, incl, blocksum);
    scanC_kernel<<<SCAN_NBLK, 256, 0, stream>>>(deg, incl, blocksum, row_start);

    // layer 1 (gemm1 before scatter_w so as1/ad1 feed the weight compute)
    gemm1_kernel<<<N_NODES / 16, 256, 0, stream>>>(x, Bp1, a_src1, a_dst1, h1b, as1, ad1);
    scatter_w_kernel<<<EB, 256, 0, stream>>>(ei, row_start, pos, as1, ad1, csr_src, wc);
    agg1_kernel<<<(N_NODES * 64 + 255) / 256, 256, 0, stream>>>(csr_src, row_start, h1b, wc, b1, hpb);

    // layer 2
    gemm2_kernel<<<(N_NODES + 63) / 64, 256, 0, stream>>>(hpb, Bp2, a_src2, a_dst2, h2b, as2, ad2);
    agg2_kernel<<<(N_NODES * 64 + 255) / 256, 256, 0, stream>>>(csr_src, row_start, h2b, as2, ad2, b2, out);
}

// Round 8
// 271.456 us; speedup vs baseline: 13.3515x; 1.0051x over previous
//
#include <hip/hip_runtime.h>
#include <hip/hip_bf16.h>

#define N_NODES 50000
#define N_EDGES 800000
#define E_TOT   850000   // edges + self loops
#define IN_DIM  128
#define C1      256      // HEADS*HID
#define HEADS   4
#define HID     64
#define OUT_DIM 32
#define NEG_SLOPE 0.2f
#define SCAN_NBLK 196    // ceil(50000/256)

typedef __attribute__((ext_vector_type(8))) short bf16x8;
typedef __attribute__((ext_vector_type(8))) unsigned short u16x8;
typedef __attribute__((ext_vector_type(4))) float f32x4;

__device__ __forceinline__ void edge_sd(const int* __restrict__ ei, int e, int& s, int& d) {
    if (e < N_EDGES) { s = ei[e]; d = ei[N_EDGES + e]; }
    else             { s = d = e - N_EDGES; }
}

__device__ __forceinline__ unsigned short f2bf(float f) {
    unsigned u = __float_as_uint(f);
    u += 0x7fffu + ((u >> 16) & 1u);   // RNE
    return (unsigned short)(u >> 16);
}
__device__ __forceinline__ float bf2f(unsigned short u) {
    return __uint_as_float(((unsigned)u) << 16);
}
__device__ __forceinline__ float4 bf4_to_f4(ushort4 v) {
    return make_float4(bf2f(v.x), bf2f(v.y), bf2f(v.z), bf2f(v.w));
}

// ================================================================ setup: zero deg, pack W1/W2 to bf16 B-fragment order
__global__ __launch_bounds__(256) void setup_kernel(const float* __restrict__ W1,
                                                    const float* __restrict__ W2,
                                                    unsigned short* __restrict__ Bp1,
                                                    unsigned short* __restrict__ Bp2,
                                                    int* __restrict__ deg) {
    int tid = blockIdx.x * 256 + threadIdx.x;
    if (tid < N_NODES) deg[tid] = 0;
    if (tid < IN_DIM * C1) {
        int j = tid & 7, q = (tid >> 3) & 3, n = (tid >> 5) & 255, K0 = tid >> 13;
        int k = K0 * 32 + q * 8 + j;
        Bp1[tid] = f2bf(W1[k * C1 + n]);
        if (tid < C1 * OUT_DIM) {
            int j2 = tid & 7, q2 = (tid >> 3) & 3, n2 = (tid >> 5) & 31, K02 = tid >> 10;
            int k2 = K02 * 32 + q2 * 8 + j2;
            Bp2[tid] = f2bf(W2[k2 * OUT_DIM + n2]);
        }
    }
}

// ================================================================ CSR build
__global__ __launch_bounds__(256) void deg_kernel(const int* __restrict__ ei,
                                                  int* __restrict__ deg,
                                                  int* __restrict__ pos) {
    int e = blockIdx.x * 256 + threadIdx.x;
    if (e >= E_TOT) return;
    int s, d; edge_sd(ei, e, s, d);
    pos[e] = atomicAdd(&deg[d], 1);
}

__global__ __launch_bounds__(256) void scanA_kernel(const int* __restrict__ deg,
                                                    int* __restrict__ incl,
                                                    int* __restrict__ blocksum) {
    __shared__ int sm[256];
    int t = threadIdx.x, idx = blockIdx.x * 256 + t;
    int v = (idx < N_NODES) ? deg[idx] : 0;
    sm[t] = v; __syncthreads();
#pragma unroll
    for (int off = 1; off < 256; off <<= 1) {
        int u = (t >= off) ? sm[t - off] : 0;
        __syncthreads();
        sm[t] += u;
        __syncthreads();
    }
    if (idx < N_NODES) incl[idx] = sm[t];
    if (t == 255) blocksum[blockIdx.x] = sm[t];
}

__global__ __launch_bounds__(256) void scanC_kernel(const int* __restrict__ deg,
                                                    const int* __restrict__ incl,
                                                    const int* __restrict__ blocksum,
                                                    int* __restrict__ row_start) {
    __shared__ int wsum[4];
    int t = threadIdx.x;
    int v = (t < (int)blockIdx.x) ? blocksum[t] : 0;   // blockIdx.x <= 195
#pragma unroll
    for (int m = 32; m >= 1; m >>= 1) v += __shfl_xor(v, m, 64);
    if ((t & 63) == 0) wsum[t >> 6] = v;
    __syncthreads();
    int off = wsum[0] + wsum[1] + wsum[2] + wsum[3];
    int idx = blockIdx.x * 256 + t;
    if (idx >= N_NODES) return;
    row_start[idx] = off + incl[idx] - deg[idx];
    if (idx == N_NODES - 1) row_start[N_NODES] = off + incl[idx];  // == E_TOT
}

// scatter + edge-weight compute -> one 32B record per CSR slot: {w0,w1,w2,w3, src, pad3}
__global__ __launch_bounds__(256) void scatter_w_kernel(const int* __restrict__ ei,
                                                        const int* __restrict__ row_start,
                                                        const int* __restrict__ pos,
                                                        const float* __restrict__ as1,
                                                        const float* __restrict__ ad1,
                                                        float* __restrict__ rec) {
    int e = blockIdx.x * 256 + threadIdx.x;
    if (e >= E_TOT) return;
    int s, d; edge_sd(ei, e, s, d);
    size_t p = (size_t)(row_start[d] + pos[e]) * 8;
    float4 av = *(const float4*)&as1[s * 4];
    float4 bv = *(const float4*)&ad1[d * 4];
    float l0 = av.x + bv.x, l1 = av.y + bv.y, l2 = av.z + bv.z, l3 = av.w + bv.w;
    l0 = l0 > 0.f ? l0 : NEG_SLOPE * l0;
    l1 = l1 > 0.f ? l1 : NEG_SLOPE * l1;
    l2 = l2 > 0.f ? l2 : NEG_SLOPE * l2;
    l3 = l3 > 0.f ? l3 : NEG_SLOPE * l3;
    *(float4*)&rec[p] = make_float4(__expf(l0), __expf(l1), __expf(l2), __expf(l3));
    ((int*)rec)[p + 4] = s;
}

// ================================================================ GEMM1 (MFMA bf16) + fused alpha1
__global__ __launch_bounds__(256) void gemm1_kernel(const float* __restrict__ x,
                                                    const unsigned short* __restrict__ Bp,
                                                    const float* __restrict__ a_src1,
                                                    const float* __restrict__ a_dst1,
                                                    unsigned short* __restrict__ h1b,
                                                    float* __restrict__ as1,
                                                    float* __restrict__ ad1) {
    __shared__ unsigned short xs[16][136];  // +8 pad -> 2-way LDS aliasing (free)
    const int t = threadIdx.x;
    const int row0 = blockIdx.x * 16;
    {
        int r = t >> 4, k0 = (t & 15) * 8;
        const float* xp = &x[(size_t)(row0 + r) * IN_DIM + k0];
        float4 v0 = *(const float4*)xp;
        float4 v1 = *(const float4*)(xp + 4);
        ushort4 o0, o1;
        o0.x = f2bf(v0.x); o0.y = f2bf(v0.y); o0.z = f2bf(v0.z); o0.w = f2bf(v0.w);
        o1.x = f2bf(v1.x); o1.y = f2bf(v1.y); o1.z = f2bf(v1.z); o1.w = f2bf(v1.w);
        *(ushort4*)&xs[r][k0] = o0;
        *(ushort4*)&xs[r][k0 + 4] = o1;
    }
    __syncthreads();
    const int wave = t >> 6;         // head index
    const int lane = t & 63;
    const int nl = lane & 15, q = lane >> 4;
    f32x4 acc[4];
    f32x4 z = {0.f, 0.f, 0.f, 0.f};
    acc[0] = z; acc[1] = z; acc[2] = z; acc[3] = z;
#pragma unroll
    for (int K0 = 0; K0 < 4; ++K0) {
        bf16x8 af = *(const bf16x8*)&xs[nl][K0 * 32 + q * 8];
#pragma unroll
        for (int sub = 0; sub < 4; ++sub) {
            int n = wave * 64 + sub * 16 + nl;
            bf16x8 bfv = *(const bf16x8*)&Bp[((size_t)(K0 * 256 + n) * 4 + q) * 8];
            acc[sub] = __builtin_amdgcn_mfma_f32_16x16x32_bf16(af, bfv, acc[sub], 0, 0, 0);
        }
    }
    float asv[4], adv[4];
#pragma unroll
    for (int sub = 0; sub < 4; ++sub) {
        asv[sub] = a_src1[wave * 64 + sub * 16 + nl];
        adv[sub] = a_dst1[wave * 64 + sub * 16 + nl];
    }
#pragma unroll
    for (int r = 0; r < 4; ++r) {
        int gr = row0 + q * 4 + r;   // C/D: row = quad*4 + reg, col = lane&15
        float ps = 0.f, pd = 0.f;
#pragma unroll
        for (int sub = 0; sub < 4; ++sub) {
            float v = acc[sub][r];
            h1b[(size_t)gr * C1 + wave * 64 + sub * 16 + nl] = f2bf(v);
            ps += v * asv[sub];
            pd += v * adv[sub];
        }
#pragma unroll
        for (int m = 8; m >= 1; m >>= 1) {
            ps += __shfl_xor(ps, m, 16);
            pd += __shfl_xor(pd, m, 16);
        }
        if (nl == 0) {
            as1[gr * 4 + wave] = ps;
            ad1[gr * 4 + wave] = pd;
        }
    }
}

// ================================================================ agg1: 1 wave/dst, edge records, unroll 16 + 8 + masked 8
__global__ __launch_bounds__(256) void agg1_kernel(const float* __restrict__ rec,
                                                   const int* __restrict__ row_start,
                                                   const unsigned short* __restrict__ h1b,
                                                   const float* __restrict__ b1,
                                                   unsigned short* __restrict__ hpb) {
    int n = (blockIdx.x * 256 + threadIdx.x) >> 6;
    if (n >= N_NODES) return;
    int lane = threadIdx.x & 63;
    int h = lane >> 4;
    const int* reci = (const int*)rec;
    int beg = __builtin_amdgcn_readfirstlane(row_start[n]);
    int end = __builtin_amdgcn_readfirstlane(row_start[n + 1]);
    float4 acc = make_float4(0.f, 0.f, 0.f, 0.f);
    float sumw = 0.f;
    int i = beg;
    for (; i + 16 <= end; i += 16) {            // unmasked, 16-way MLP
        int s[16]; float w[16];
#pragma unroll
        for (int u = 0; u < 16; ++u) {
            s[u] = __builtin_amdgcn_readfirstlane(reci[(size_t)(i + u) * 8 + 4]);
            w[u] = rec[(size_t)(i + u) * 8 + h];
        }
        ushort4 rv[16];
#pragma unroll
        for (int u = 0; u < 16; ++u) rv[u] = *(const ushort4*)&h1b[(size_t)s[u] * C1 + lane * 4];
#pragma unroll
        for (int u = 0; u < 16; ++u) {
            sumw += w[u];
            float4 f = bf4_to_f4(rv[u]);
            acc.x += w[u] * f.x; acc.y += w[u] * f.y;
            acc.z += w[u] * f.z; acc.w += w[u] * f.w;
        }
    }
    if (i + 8 <= end) {                          // unmasked, 8-way
        int s[8]; float w[8];
#pragma unroll
        for (int u = 0; u < 8; ++u) {
            s[u] = __builtin_amdgcn_readfirstlane(reci[(size_t)(i + u) * 8 + 4]);
            w[u] = rec[(size_t)(i + u) * 8 + h];
        }
        ushort4 rv[8];
#pragma unroll
        for (int u = 0; u < 8; ++u) rv[u] = *(const ushort4*)&h1b[(size_t)s[u] * C1 + lane * 4];
#pragma unroll
        for (int u = 0; u < 8; ++u) {
            sumw += w[u];
            float4 f = bf4_to_f4(rv[u]);
            acc.x += w[u] * f.x; acc.y += w[u] * f.y;
            acc.z += w[u] * f.z; acc.w += w[u] * f.w;
        }
        i += 8;
    }
    if (i < end) {                               // masked tail, 8-way
        int s[8]; float w[8];
#pragma unroll
        for (int u = 0; u < 8; ++u) {
            bool va = (i + u) < end;
            int ic = va ? i + u : beg;           // safe slot (deg >= 1 via self-loop)
            s[u] = __builtin_amdgcn_readfirstlane(reci[(size_t)ic * 8 + 4]);
            w[u] = va ? rec[(size_t)ic * 8 + h] : 0.f;
        }
        ushort4 rv[8];
#pragma unroll
        for (int u = 0; u < 8; ++u) rv[u] = *(const ushort4*)&h1b[(size_t)s[u] * C1 + lane * 4];
#pragma unroll
        for (int u = 0; u < 8; ++u) {
            sumw += w[u];
            float4 f = bf4_to_f4(rv[u]);
            acc.x += w[u] * f.x; acc.y += w[u] * f.y;
            acc.z += w[u] * f.z; acc.w += w[u] * f.w;
        }
    }
    float inv = 1.f / (sumw + 1e-16f);
    const float4 bv = *(const float4*)&b1[lane * 4];
    float v0 = acc.x * inv + bv.x;
    float v1 = acc.y * inv + bv.y;
    float v2 = acc.z * inv + bv.z;
    float v3 = acc.w * inv + bv.w;
    v0 = v0 > 0.f ? v0 : __expf(v0) - 1.f;
    v1 = v1 > 0.f ? v1 : __expf(v1) - 1.f;
    v2 = v2 > 0.f ? v2 : __expf(v2) - 1.f;
    v3 = v3 > 0.f ? v3 : __expf(v3) - 1.f;
    ushort4 o;
    o.x = f2bf(v0); o.y = f2bf(v1); o.z = f2bf(v2); o.w = f2bf(v3);
    *(ushort4*)&hpb[(size_t)n * C1 + lane * 4] = o;
}

// ================================================================ GEMM2 (MFMA bf16) + fused alpha2; h2 stored bf16
__global__ __launch_bounds__(256) void gemm2_kernel(const unsigned short* __restrict__ hpb,
                                                    const unsigned short* __restrict__ Bp2,
                                                    const float* __restrict__ a_src2,
                                                    const float* __restrict__ a_dst2,
                                                    unsigned short* __restrict__ h2b,
                                                    float* __restrict__ as2,
                                                    float* __restrict__ ad2) {
    __shared__ unsigned short xs[64][264];  // stride 264 shorts -> 2-way bank aliasing (free)
    const int t = threadIdx.x;
    const int row0 = blockIdx.x * 64;
    for (int idx = t; idx < 2048; idx += 256) {  // 64 rows x 32 chunks of 8
        int r = idx >> 5, ch = (idx & 31) * 8;
        int gr = row0 + r;
        u16x8 v = {0, 0, 0, 0, 0, 0, 0, 0};
        if (gr < N_NODES) v = *(const u16x8*)&hpb[(size_t)gr * C1 + ch];
        *(u16x8*)&xs[r][ch] = v;
    }
    __syncthreads();
    const int wave = t >> 6, lane = t & 63;
    const int nl = lane & 15, q = lane >> 4;
    f32x4 acc0 = {0.f, 0.f, 0.f, 0.f}, acc1 = {0.f, 0.f, 0.f, 0.f};
#pragma unroll
    for (int K0 = 0; K0 < 8; ++K0) {
        bf16x8 af = *(const bf16x8*)&xs[wave * 16 + nl][K0 * 32 + q * 8];
        bf16x8 b0 = *(const bf16x8*)&Bp2[((size_t)(K0 * 32 + nl) * 4 + q) * 8];
        bf16x8 b1v = *(const bf16x8*)&Bp2[((size_t)(K0 * 32 + 16 + nl) * 4 + q) * 8];
        acc0 = __builtin_amdgcn_mfma_f32_16x16x32_bf16(af, b0, acc0, 0, 0, 0);
        acc1 = __builtin_amdgcn_mfma_f32_16x16x32_bf16(af, b1v, acc1, 0, 0, 0);
    }
    float a_s0 = a_src2[nl], a_s1 = a_src2[16 + nl];
    float a_d0 = a_dst2[nl], a_d1 = a_dst2[16 + nl];
#pragma unroll
    for (int r = 0; r < 4; ++r) {
        int gr = row0 + wave * 16 + q * 4 + r;
        if (gr < N_NODES) {
            h2b[(size_t)gr * OUT_DIM + nl] = f2bf(acc0[r]);
            h2b[(size_t)gr * OUT_DIM + 16 + nl] = f2bf(acc1[r]);
            float ps = acc0[r] * a_s0 + acc1[r] * a_s1;
            float pd = acc0[r] * a_d0 + acc1[r] * a_d1;
#pragma unroll
            for (int m = 8; m >= 1; m >>= 1) {
                ps += __shfl_xor(ps, m, 16);
                pd += __shfl_xor(pd, m, 16);
            }
            if (nl == 0) { as2[gr] = ps; ad2[gr] = pd; }
        }
    }
}

// ================================================================ agg2: 1 wave/dst, 2x8 edges x 8 lanes x ushort4 (bf16 h2)
__global__ __launch_bounds__(256) void agg2_kernel(const float* __restrict__ rec,
                                                   const int* __restrict__ row_start,
                                                   const unsigned short* __restrict__ h2b,
                                                   const float* __restrict__ as2,
                                                   const float* __restrict__ ad2,
                                                   const float* __restrict__ b2,
                                                   float* __restrict__ out) {
    int n = (blockIdx.x * 256 + threadIdx.x) >> 6;
    if (n >= N_NODES) return;
    int lane = threadIdx.x & 63;
    int g  = lane >> 3;          // edge slot 0..7
    int c4 = lane & 7;           // ushort4 chunk: cols [c4*4, c4*4+4)
    const int* reci = (const int*)rec;
    int beg = __builtin_amdgcn_readfirstlane(row_start[n]);
    int end = __builtin_amdgcn_readfirstlane(row_start[n + 1]);
    float ad = ad2[n];
    float4 acc = make_float4(0.f, 0.f, 0.f, 0.f);
    float sumw = 0.f;
    for (int i = beg; i < end; i += 16) {        // two 8-edge batches in flight
#pragma unroll
        for (int b = 0; b < 2; ++b) {
            int idx = i + b * 8 + g;
            bool valid = idx < end;
            int ic = valid ? idx : beg;
            int s = reci[(size_t)ic * 8 + 4];
            float l = as2[s] + ad;
            l = l > 0.f ? l : NEG_SLOPE * l;
            float w = valid ? __expf(l) : 0.f;
            sumw += w;
            float4 hv = bf4_to_f4(*(const ushort4*)&h2b[(size_t)s * OUT_DIM + c4 * 4]);
            acc.x += w * hv.x; acc.y += w * hv.y; acc.z += w * hv.z; acc.w += w * hv.w;
        }
    }
#pragma unroll
    for (int m = 8; m <= 32; m <<= 1) {
        sumw  += __shfl_xor(sumw, m, 64);
        acc.x += __shfl_xor(acc.x, m, 64);
        acc.y += __shfl_xor(acc.y, m, 64);
        acc.z += __shfl_xor(acc.z, m, 64);
        acc.w += __shfl_xor(acc.w, m, 64);
    }
    if (g == 0) {
        float inv = 1.f / (sumw + 1e-16f);
        const float4 bv = *(const float4*)&b2[c4 * 4];
        *(float4*)&out[(size_t)n * OUT_DIM + c4 * 4] =
            make_float4(acc.x * inv + bv.x, acc.y * inv + bv.y,
                        acc.z * inv + bv.z, acc.w * inv + bv.w);
    }
}

extern "C" void kernel_launch(void* const* d_in, const int* in_sizes, int n_in,
                              void* d_out, int out_size, void* d_ws, size_t ws_size,
                              hipStream_t stream) {
    const float* x      = (const float*)d_in[0];
    const int*   ei     = (const int*)d_in[1];
    const float* W1     = (const float*)d_in[2];
    const float* a_src1 = (const float*)d_in[3];
    const float* a_dst1 = (const float*)d_in[4];
    const float* b1     = (const float*)d_in[5];
    const float* W2     = (const float*)d_in[6];
    const float* a_src2 = (const float*)d_in[7];
    const float* a_dst2 = (const float*)d_in[8];
    const float* b2     = (const float*)d_in[9];
    float* out = (float*)d_out;

    // workspace layout (all segment boundaries 32B-aligned)
    unsigned short* h1b = (unsigned short*)d_ws;        // 12.8M bf16
    unsigned short* hpb = h1b + 12800000;               // 12.8M bf16
    unsigned short* h2b = hpb + 12800000;               // 1.6M bf16
    unsigned short* Bp1 = h2b + 1600000;                // 32768 bf16
    unsigned short* Bp2 = Bp1 + 32768;                  // 8192 bf16
    float* as1    = (float*)(Bp2 + 8192);               // 200k
    float* ad1    = as1 + 200000;                       // 200k
    float* as2    = ad1 + 200000;                       // 50k
    float* ad2    = as2 + 50000;                        // 50k
    float* rec    = ad2 + 50000;                        // E_TOT * 8 floats (27.2 MB), 32B records
    int* row_start= (int*)(rec + (size_t)E_TOT * 8);    // 50001
    int* deg      = row_start + (N_NODES + 1);          // 50k
    int* pos      = deg + N_NODES;                      // 850k
    int* incl     = pos + E_TOT;                        // 50k
    int* blocksum = incl + N_NODES;                     // 256

    const int EB = (E_TOT + 255) / 256;
    setup_kernel<<<SCAN_NBLK, 256, 0, stream>>>(W1, W2, Bp1, Bp2, deg);  // zeros deg
    deg_kernel<<<EB, 256, 0, stream>>>(ei, deg, pos);
    scanA_kernel<<<SCAN_NBLK, 256, 0, stream>>>(deg, incl, blocksum);
    scanC_kernel<<<SCAN_NBLK, 256, 0, stream>>>(deg, incl, blocksum, row_start);

    // layer 1 (gemm1 before scatter_w so as1/ad1 feed the weight compute)
    gemm1_kernel<<<N_NODES / 16, 256, 0, stream>>>(x, Bp1, a_src1, a_dst1, h1b, as1, ad1);
    scatter_w_kernel<<<EB, 256, 0, stream>>>(ei, row_start, pos, as1, ad1, rec);
    agg1_kernel<<<(N_NODES * 64 + 255) / 256, 256, 0, stream>>>(rec, row_start, h1b, b1, hpb);

    // layer 2
    gemm2_kernel<<<(N_NODES + 63) / 64, 256, 0, stream>>>(hpb, Bp2, a_src2, a_dst2, h2b, as2, ad2);
    agg2_kernel<<<(N_NODES * 64 + 255) / 256, 256, 0, stream>>>(rec, row_start, h2b, as2, ad2, b2, out);
}

// Round 9
// 251.362 us; speedup vs baseline: 14.4188x; 1.0799x over previous
//
#include <hip/hip_runtime.h>
#include <hip/hip_bf16.h>

#define N_NODES 50000
#define N_EDGES 800000
#define E_TOT   850000   // edges + self loops
#define IN_DIM  128
#define C1      256      // HEADS*HID
#define HEADS   4
#define HID     64
#define OUT_DIM 32
#define NEG_SLOPE 0.2f
#define SCAN_NBLK 196    // ceil(50000/256)
#define G1_BLOCKS 3125   // 50000/16
#define EDGES_PER_G1 272 // 850000/3125

typedef __attribute__((ext_vector_type(8))) short bf16x8;
typedef __attribute__((ext_vector_type(8))) unsigned short u16x8;
typedef __attribute__((ext_vector_type(4))) float f32x4;

__device__ __forceinline__ void edge_sd(const int* __restrict__ ei, int e, int& s, int& d) {
    if (e < N_EDGES) { s = ei[e]; d = ei[N_EDGES + e]; }
    else             { s = d = e - N_EDGES; }
}

__device__ __forceinline__ unsigned short f2bf(float f) {
    unsigned u = __float_as_uint(f);
    u += 0x7fffu + ((u >> 16) & 1u);   // RNE
    return (unsigned short)(u >> 16);
}
__device__ __forceinline__ float bf2f(unsigned short u) {
    return __uint_as_float(((unsigned)u) << 16);
}
__device__ __forceinline__ float4 bf4_to_f4(ushort4 v) {
    return make_float4(bf2f(v.x), bf2f(v.y), bf2f(v.z), bf2f(v.w));
}
__device__ __forceinline__ float lrelu_exp(float l) {
    return __expf(fmaxf(l, NEG_SLOPE * l));   // slope<1 => lrelu == max(l, 0.2l)
}

// ================================================================ setup: zero deg+counter, pack W1/W2 (bf16 B-fragment order)
__global__ __launch_bounds__(256) void setup_kernel(const float* __restrict__ W1,
                                                    const float* __restrict__ W2,
                                                    unsigned short* __restrict__ Bp1,
                                                    unsigned short* __restrict__ Bp2,
                                                    int* __restrict__ deg) {
    int tid = blockIdx.x * 256 + threadIdx.x;
    if (tid < N_NODES + 1) deg[tid] = 0;   // deg[50000] doubles as the scan arrival counter
    if (tid < IN_DIM * C1) {
        int j = tid & 7, q = (tid >> 3) & 3, n = (tid >> 5) & 255, K0 = tid >> 13;
        int k = K0 * 32 + q * 8 + j;
        Bp1[tid] = f2bf(W1[k * C1 + n]);
        if (tid < C1 * OUT_DIM) {
            int j2 = tid & 7, q2 = (tid >> 3) & 3, n2 = (tid >> 5) & 31, K02 = tid >> 10;
            int k2 = K02 * 32 + q2 * 8 + j2;
            Bp2[tid] = f2bf(W2[k2 * OUT_DIM + n2]);
        }
    }
}

// ================================================================ GEMM1 (MFMA bf16) + fused alpha1 + fused edge-degree count
__global__ __launch_bounds__(256) void gemm1_kernel(const float* __restrict__ x,
                                                    const unsigned short* __restrict__ Bp,
                                                    const float* __restrict__ a_src1,
                                                    const float* __restrict__ a_dst1,
                                                    const int* __restrict__ ei,
                                                    unsigned short* __restrict__ h1b,
                                                    float* __restrict__ as1,
                                                    float* __restrict__ ad1,
                                                    int* __restrict__ deg,
                                                    int* __restrict__ pos) {
    __shared__ unsigned short xs[16][136];  // +8 pad -> 2-way LDS aliasing (free)
    const int t = threadIdx.x;
    const int row0 = blockIdx.x * 16;
    {
        int r = t >> 4, k0 = (t & 15) * 8;
        const float* xp = &x[(size_t)(row0 + r) * IN_DIM + k0];
        float4 v0 = *(const float4*)xp;
        float4 v1 = *(const float4*)(xp + 4);
        ushort4 o0, o1;
        o0.x = f2bf(v0.x); o0.y = f2bf(v0.y); o0.z = f2bf(v0.z); o0.w = f2bf(v0.w);
        o1.x = f2bf(v1.x); o1.y = f2bf(v1.y); o1.z = f2bf(v1.z); o1.w = f2bf(v1.w);
        *(ushort4*)&xs[r][k0] = o0;
        *(ushort4*)&xs[r][k0 + 4] = o1;
    }
    __syncthreads();
    const int wave = t >> 6;         // head index
    const int lane = t & 63;
    const int nl = lane & 15, q = lane >> 4;
    f32x4 acc[4];
    f32x4 z = {0.f, 0.f, 0.f, 0.f};
    acc[0] = z; acc[1] = z; acc[2] = z; acc[3] = z;
#pragma unroll
    for (int K0 = 0; K0 < 4; ++K0) {
        bf16x8 af = *(const bf16x8*)&xs[nl][K0 * 32 + q * 8];
#pragma unroll
        for (int sub = 0; sub < 4; ++sub) {
            int n = wave * 64 + sub * 16 + nl;
            bf16x8 bfv = *(const bf16x8*)&Bp[((size_t)(K0 * 256 + n) * 4 + q) * 8];
            acc[sub] = __builtin_amdgcn_mfma_f32_16x16x32_bf16(af, bfv, acc[sub], 0, 0, 0);
        }
    }
    float asv[4], adv[4];
#pragma unroll
    for (int sub = 0; sub < 4; ++sub) {
        asv[sub] = a_src1[wave * 64 + sub * 16 + nl];
        adv[sub] = a_dst1[wave * 64 + sub * 16 + nl];
    }
#pragma unroll
    for (int r = 0; r < 4; ++r) {
        int gr = row0 + q * 4 + r;   // C/D: row = quad*4 + reg, col = lane&15
        float ps = 0.f, pd = 0.f;
#pragma unroll
        for (int sub = 0; sub < 4; ++sub) {
            float v = acc[sub][r];
            h1b[(size_t)gr * C1 + wave * 64 + sub * 16 + nl] = f2bf(v);
            ps += v * asv[sub];
            pd += v * adv[sub];
        }
#pragma unroll
        for (int m = 8; m >= 1; m >>= 1) {
            ps += __shfl_xor(ps, m, 16);
            pd += __shfl_xor(pd, m, 16);
        }
        if (nl == 0) {
            as1[gr * 4 + wave] = ps;
            ad1[gr * 4 + wave] = pd;
        }
    }
    // fused degree count: this block's 272-edge slice
    int base = blockIdx.x * EDGES_PER_G1;
    for (int e = base + t; e < base + EDGES_PER_G1; e += 256) {
        int s, d; edge_sd(ei, e, s, d);
        pos[e] = atomicAdd(&deg[d], 1);
    }
}

// ================================================================ scan: block-local scan + arrival-order chunk base
// row_start[n] = chunk_base + exclusive_prefix(deg within chunk). Disjoint, not monotonic across chunks.
__global__ __launch_bounds__(256) void scan_kernel(const int* __restrict__ deg,
                                                   int* __restrict__ counter,  // = &deg[50000], zeroed
                                                   int* __restrict__ row_start) {
    __shared__ int sm[256];
    __shared__ int base;
    int t = threadIdx.x, idx = blockIdx.x * 256 + t;
    int v = (idx < N_NODES) ? deg[idx] : 0;
    sm[t] = v; __syncthreads();
#pragma unroll
    for (int off = 1; off < 256; off <<= 1) {
        int u = (t >= off) ? sm[t - off] : 0;
        __syncthreads();
        sm[t] += u;
        __syncthreads();
    }
    if (t == 255) base = atomicAdd(counter, sm[255]);
    __syncthreads();
    if (idx < N_NODES) row_start[idx] = base + sm[t] - v;
}

// ================================================================ scatter: csr_src only (4 B/edge)
__global__ __launch_bounds__(256) void scatter_kernel(const int* __restrict__ ei,
                                                      const int* __restrict__ row_start,
                                                      const int* __restrict__ pos,
                                                      int* __restrict__ csr_src) {
    int e = blockIdx.x * 256 + threadIdx.x;
    if (e >= E_TOT) return;
    int s, d; edge_sd(ei, e, s, d);
    csr_src[row_start[d] + pos[e]] = s;
}

// ================================================================ agg1: 1 wave/dst, inline w, scalar addressing, unroll 16/8/8
__global__ __launch_bounds__(256) void agg1_kernel(const int* __restrict__ csr_src,
                                                   const int* __restrict__ row_start,
                                                   const int* __restrict__ deg,
                                                   const unsigned short* __restrict__ h1b,
                                                   const float* __restrict__ as1,
                                                   const float* __restrict__ ad1,
                                                   const float* __restrict__ b1,
                                                   unsigned short* __restrict__ hpb) {
    int n = (blockIdx.x * 256 + threadIdx.x) >> 6;
    if (n >= N_NODES) return;
    int lane = threadIdx.x & 63;
    int h = lane >> 4;
    int beg = __builtin_amdgcn_readfirstlane(row_start[n]);
    int end = beg + __builtin_amdgcn_readfirstlane(deg[n]);
    float ad = ad1[n * 4 + h];
    float4 acc = make_float4(0.f, 0.f, 0.f, 0.f);
    float sumw = 0.f;
    int i = beg;
    for (; i + 16 <= end; i += 16) {            // unmasked, 16-way MLP
        int s[16];
#pragma unroll
        for (int u = 0; u < 16; ++u) s[u] = __builtin_amdgcn_readfirstlane(csr_src[i + u]);
        float a[16];
#pragma unroll
        for (int u = 0; u < 16; ++u) a[u] = as1[s[u] * 4 + h];
        ushort4 rv[16];
#pragma unroll
        for (int u = 0; u < 16; ++u) rv[u] = *(const ushort4*)&h1b[(size_t)s[u] * C1 + lane * 4];
#pragma unroll
        for (int u = 0; u < 16; ++u) {
            float w = lrelu_exp(a[u] + ad);
            sumw += w;
            float4 f = bf4_to_f4(rv[u]);
            acc.x += w * f.x; acc.y += w * f.y;
            acc.z += w * f.z; acc.w += w * f.w;
        }
    }
    if (i + 8 <= end) {                          // unmasked, 8-way
        int s[8];
#pragma unroll
        for (int u = 0; u < 8; ++u) s[u] = __builtin_amdgcn_readfirstlane(csr_src[i + u]);
        float a[8];
#pragma unroll
        for (int u = 0; u < 8; ++u) a[u] = as1[s[u] * 4 + h];
        ushort4 rv[8];
#pragma unroll
        for (int u = 0; u < 8; ++u) rv[u] = *(const ushort4*)&h1b[(size_t)s[u] * C1 + lane * 4];
#pragma unroll
        for (int u = 0; u < 8; ++u) {
            float w = lrelu_exp(a[u] + ad);
            sumw += w;
            float4 f = bf4_to_f4(rv[u]);
            acc.x += w * f.x; acc.y += w * f.y;
            acc.z += w * f.z; acc.w += w * f.w;
        }
        i += 8;
    }
    if (i < end) {                               // masked tail, 8-way
        int s[8]; float va[8];
#pragma unroll
        for (int u = 0; u < 8; ++u) {
            bool v = (i + u) < end;
            va[u] = v ? 1.f : 0.f;
            s[u] = __builtin_amdgcn_readfirstlane(csr_src[v ? i + u : beg]);
        }
        float a[8];
#pragma unroll
        for (int u = 0; u < 8; ++u) a[u] = as1[s[u] * 4 + h];
        ushort4 rv[8];
#pragma unroll
        for (int u = 0; u < 8; ++u) rv[u] = *(const ushort4*)&h1b[(size_t)s[u] * C1 + lane * 4];
#pragma unroll
        for (int u = 0; u < 8; ++u) {
            float w = va[u] * lrelu_exp(a[u] + ad);
            sumw += w;
            float4 f = bf4_to_f4(rv[u]);
            acc.x += w * f.x; acc.y += w * f.y;
            acc.z += w * f.z; acc.w += w * f.w;
        }
    }
    float inv = 1.f / (sumw + 1e-16f);
    const float4 bv = *(const float4*)&b1[lane * 4];
    float v0 = acc.x * inv + bv.x;
    float v1 = acc.y * inv + bv.y;
    float v2 = acc.z * inv + bv.z;
    float v3 = acc.w * inv + bv.w;
    v0 = v0 > 0.f ? v0 : __expf(v0) - 1.f;
    v1 = v1 > 0.f ? v1 : __expf(v1) - 1.f;
    v2 = v2 > 0.f ? v2 : __expf(v2) - 1.f;
    v3 = v3 > 0.f ? v3 : __expf(v3) - 1.f;
    ushort4 o;
    o.x = f2bf(v0); o.y = f2bf(v1); o.z = f2bf(v2); o.w = f2bf(v3);
    *(ushort4*)&hpb[(size_t)n * C1 + lane * 4] = o;
}

// ================================================================ GEMM2 (MFMA bf16) + fused alpha2; h2 stored bf16
__global__ __launch_bounds__(256) void gemm2_kernel(const unsigned short* __restrict__ hpb,
                                                    const unsigned short* __restrict__ Bp2,
                                                    const float* __restrict__ a_src2,
                                                    const float* __restrict__ a_dst2,
                                                    unsigned short* __restrict__ h2b,
                                                    float* __restrict__ as2,
                                                    float* __restrict__ ad2) {
    __shared__ unsigned short xs[64][264];  // stride 264 shorts -> 2-way bank aliasing (free)
    const int t = threadIdx.x;
    const int row0 = blockIdx.x * 64;
    for (int idx = t; idx < 2048; idx += 256) {  // 64 rows x 32 chunks of 8
        int r = idx >> 5, ch = (idx & 31) * 8;
        int gr = row0 + r;
        u16x8 v = {0, 0, 0, 0, 0, 0, 0, 0};
        if (gr < N_NODES) v = *(const u16x8*)&hpb[(size_t)gr * C1 + ch];
        *(u16x8*)&xs[r][ch] = v;
    }
    __syncthreads();
    const int wave = t >> 6, lane = t & 63;
    const int nl = lane & 15, q = lane >> 4;
    f32x4 acc0 = {0.f, 0.f, 0.f, 0.f}, acc1 = {0.f, 0.f, 0.f, 0.f};
#pragma unroll
    for (int K0 = 0; K0 < 8; ++K0) {
        bf16x8 af = *(const bf16x8*)&xs[wave * 16 + nl][K0 * 32 + q * 8];
        bf16x8 b0 = *(const bf16x8*)&Bp2[((size_t)(K0 * 32 + nl) * 4 + q) * 8];
        bf16x8 b1v = *(const bf16x8*)&Bp2[((size_t)(K0 * 32 + 16 + nl) * 4 + q) * 8];
        acc0 = __builtin_amdgcn_mfma_f32_16x16x32_bf16(af, b0, acc0, 0, 0, 0);
        acc1 = __builtin_amdgcn_mfma_f32_16x16x32_bf16(af, b1v, acc1, 0, 0, 0);
    }
    float a_s0 = a_src2[nl], a_s1 = a_src2[16 + nl];
    float a_d0 = a_dst2[nl], a_d1 = a_dst2[16 + nl];
#pragma unroll
    for (int r = 0; r < 4; ++r) {
        int gr = row0 + wave * 16 + q * 4 + r;
        if (gr < N_NODES) {
            h2b[(size_t)gr * OUT_DIM + nl] = f2bf(acc0[r]);
            h2b[(size_t)gr * OUT_DIM + 16 + nl] = f2bf(acc1[r]);
            float ps = acc0[r] * a_s0 + acc1[r] * a_s1;
            float pd = acc0[r] * a_d0 + acc1[r] * a_d1;
#pragma unroll
            for (int m = 8; m >= 1; m >>= 1) {
                ps += __shfl_xor(ps, m, 16);
                pd += __shfl_xor(pd, m, 16);
            }
            if (nl == 0) { as2[gr] = ps; ad2[gr] = pd; }
        }
    }
}

// ================================================================ agg2: 1 wave/dst, 2x8 edges x 8 lanes x ushort4 (bf16 h2)
__global__ __launch_bounds__(256) void agg2_kernel(const int* __restrict__ csr_src,
                                                   const int* __restrict__ row_start,
                                                   const int* __restrict__ deg,
                                                   const unsigned short* __restrict__ h2b,
                                                   const float* __restrict__ as2,
                                                   const float* __restrict__ ad2,
                                                   const float* __restrict__ b2,
                                                   float* __restrict__ out) {
    int n = (blockIdx.x * 256 + threadIdx.x) >> 6;
    if (n >= N_NODES) return;
    int lane = threadIdx.x & 63;
    int g  = lane >> 3;          // edge slot 0..7
    int c4 = lane & 7;           // ushort4 chunk: cols [c4*4, c4*4+4)
    int beg = __builtin_amdgcn_readfirstlane(row_start[n]);
    int end = beg + __builtin_amdgcn_readfirstlane(deg[n]);
    float ad = ad2[n];
    float4 acc = make_float4(0.f, 0.f, 0.f, 0.f);
    float sumw = 0.f;
    for (int i = beg; i < end; i += 16) {        // two 8-edge batches in flight
#pragma unroll
        for (int b = 0; b < 2; ++b) {
            int idx = i + b * 8 + g;
            bool valid = idx < end;
            int ic = valid ? idx : beg;
            int s = csr_src[ic];
            float w = valid ? lrelu_exp(as2[s] + ad) : 0.f;
            sumw += w;
            float4 hv = bf4_to_f4(*(const ushort4*)&h2b[(size_t)s * OUT_DIM + c4 * 4]);
            acc.x += w * hv.x; acc.y += w * hv.y; acc.z += w * hv.z; acc.w += w * hv.w;
        }
    }
#pragma unroll
    for (int m = 8; m <= 32; m <<= 1) {
        sumw  += __shfl_xor(sumw, m, 64);
        acc.x += __shfl_xor(acc.x, m, 64);
        acc.y += __shfl_xor(acc.y, m, 64);
        acc.z += __shfl_xor(acc.z, m, 64);
        acc.w += __shfl_xor(acc.w, m, 64);
    }
    if (g == 0) {
        float inv = 1.f / (sumw + 1e-16f);
        const float4 bv = *(const float4*)&b2[c4 * 4];
        *(float4*)&out[(size_t)n * OUT_DIM + c4 * 4] =
            make_float4(acc.x * inv + bv.x, acc.y * inv + bv.y,
                        acc.z * inv + bv.z, acc.w * inv + bv.w);
    }
}

extern "C" void kernel_launch(void* const* d_in, const int* in_sizes, int n_in,
                              void* d_out, int out_size, void* d_ws, size_t ws_size,
                              hipStream_t stream) {
    const float* x      = (const float*)d_in[0];
    const int*   ei     = (const int*)d_in[1];
    const float* W1     = (const float*)d_in[2];
    const float* a_src1 = (const float*)d_in[3];
    const float* a_dst1 = (const float*)d_in[4];
    const float* b1     = (const float*)d_in[5];
    const float* W2     = (const float*)d_in[6];
    const float* a_src2 = (const float*)d_in[7];
    const float* a_dst2 = (const float*)d_in[8];
    const float* b2     = (const float*)d_in[9];
    float* out = (float*)d_out;

    // workspace layout
    unsigned short* h1b = (unsigned short*)d_ws;        // 12.8M bf16
    unsigned short* hpb = h1b + 12800000;               // 12.8M bf16
    unsigned short* h2b = hpb + 12800000;               // 1.6M bf16
    unsigned short* Bp1 = h2b + 1600000;                // 32768 bf16
    unsigned short* Bp2 = Bp1 + 32768;                  // 8192 bf16
    float* as1    = (float*)(Bp2 + 8192);               // 200k
    float* ad1    = as1 + 200000;                       // 200k
    float* as2    = ad1 + 200000;                       // 50k
    float* ad2    = as2 + 50000;                        // 50k
    int* csr_src  = (int*)(ad2 + 50000);                // 850k
    int* row_start= csr_src + E_TOT;                    // 50000
    int* deg      = row_start + N_NODES;                // 50001 (last = scan counter)
    int* pos      = deg + N_NODES + 1;                  // 850k

    setup_kernel<<<SCAN_NBLK, 256, 0, stream>>>(W1, W2, Bp1, Bp2, deg);
    gemm1_kernel<<<G1_BLOCKS, 256, 0, stream>>>(x, Bp1, a_src1, a_dst1, ei,
                                                h1b, as1, ad1, deg, pos);
    scan_kernel<<<SCAN_NBLK, 256, 0, stream>>>(deg, deg + N_NODES, row_start);
    scatter_kernel<<<(E_TOT + 255) / 256, 256, 0, stream>>>(ei, row_start, pos, csr_src);
    agg1_kernel<<<(N_NODES * 64 + 255) / 256, 256, 0, stream>>>(csr_src, row_start, deg,
                                                                h1b, as1, ad1, b1, hpb);
    gemm2_kernel<<<(N_NODES + 63) / 64, 256, 0, stream>>>(hpb, Bp2, a_src2, a_dst2, h2b, as2, ad2);
    agg2_kernel<<<(N_NODES * 64 + 255) / 256, 256, 0, stream>>>(csr_src, row_start, deg,
                                                                h2b, as2, ad2, b2, out);
}